// Round 2
// baseline (3929.977 us; speedup 1.0000x reference)
//
#include <hip/hip_runtime.h>
#include <hip/hip_bf16.h>
#include <math.h>

#define DEV static __device__ __forceinline__

DEV float geluf(float x){ return 0.5f*x*(1.0f + erff(x*0.70710678118654752f)); }
DEV float sigmf(float x){ return 1.0f/(1.0f + __expf(-x)); }
DEV float softplusf(float x){ return (x > 15.f) ? x : log1pf(__expf(x)); }

// ---------------- workspace layout (float offsets) ----------------
enum : size_t {
  OFF_W1F   = 0,        // 2048  folded enc conv1 weights (256x8)
  OFF_B1F   = 2048,     // 256
  OFF_S2E   = 2304,     // 64
  OFF_B2E   = 2368,     // 64
  OFF_WIHT  = 2432,     // 32768 w_ih^T (64x512)
  OFF_BIASG = 35200,    // 512   b_ih+b_hh
  OFF_WHHT  = 35712,    // 65536 w_hh^T (128x512)
  OFF_EPI1S = 101248,   // 128
  OFF_EPI1B = 101376,   // 128
  OFF_EPI2S = 101504,   // 256
  OFF_EPI2B = 101760,   // 256
  OFF_EPI3S = 102016,   // 128
  OFF_EPI3B = 102144,   // 128
  OFF_XSRC  = 364416,   // 524288 (B,T,64)
  OFF_GX    = 888704,   // 4194304 (B,T,512)
  OFF_HSEQ  = 5083008,  // 1048576 (B,T,128)
  OFF_HN    = 6131584,  // 1048576
  OFF_PCOL  = 7180160,  // 8192
  OFF_CCOL  = 7188352,  // 8192
  OFF_CUTS  = 7196544,  // 32 (int)
  OFF_LAST  = 7196576,  // 4096
  OFF_CORR  = 7200672,  // 4096
  OFF_FEATA = 7204768,  // 28672 (B,128,7)
  OFF_MUO   = 7233440,  // 4096
  OFF_STDO  = 7237536,  // 4096
  OFF_XZ    = 7241632,  // 8192 (B,256)
  OFF_FEATB = 7249824,  // 57344 (B,256,7)
  OFF_MUCO  = 7307168,  // 4096
  OFF_STDCO = 7311264,  // 4096
  OFF_XC1   = 7315360,  // 131072 (B,128,32)
  OFF_XC2   = 7446432,  // 262144 (B,256,32)
  OFF_XC3   = 7708576,  // 131072
  OFF_X2F   = 7839648,  // 4096
  OFF_XALL  = 7843744,  // 8192
  OFF_FEATC = 7851936,  // 57344
  WS_FLOATS = 7909280   // ~31.6 MB
};

// ---------------- prep: fold BN, transpose LSTM weights ----------------
__global__ __launch_bounds__(256) void prep_kernel(
    const float* we1, const float* be1,
    const float* e1g, const float* e1b, const float* e1m, const float* e1v,
    const float* be2, const float* e2g, const float* e2b, const float* e2m, const float* e2v,
    const float* wih, const float* whh, const float* bih, const float* bhh,
    const float* bc1, const float* c1g, const float* c1b, const float* c1m, const float* c1v,
    const float* bc2, const float* c2g, const float* c2b, const float* c2m, const float* c2v,
    const float* bc3, const float* c3g, const float* c3b, const float* c3m, const float* c3v,
    float* ws)
{
  int idx = blockIdx.x*256 + threadIdx.x;
  if(idx < 2048){
    int o = idx>>3;
    float s = e1g[o] * rsqrtf(e1v[o] + 1e-5f);
    ws[OFF_W1F + idx] = we1[idx] * s;
  } else if(idx < 2304){
    int o = idx - 2048;
    float s = e1g[o] * rsqrtf(e1v[o] + 1e-5f);
    ws[OFF_B1F + o] = s*(be1[o] - e1m[o]) + e1b[o];
  } else if(idx < 2368){
    int e = idx - 2304;
    float s = e2g[e] * rsqrtf(e2v[e] + 1e-5f);
    ws[OFF_S2E + e] = s;
    ws[OFF_B2E + e] = s*(be2[e] - e2m[e]) + e2b[e];
  } else if(idx < 35136){
    int q = idx - 2368; int e = q>>9, g = q&511;
    ws[OFF_WIHT + q] = wih[g*64 + e];
  } else if(idx < 35648){
    int g = idx - 35136;
    ws[OFF_BIASG + g] = bih[g] + bhh[g];
  } else if(idx < 101184){
    int q = idx - 35648; int k = q>>9, g = q&511;
    ws[OFF_WHHT + q] = whh[g*128 + k];
  } else if(idx < 101312){
    int o = idx - 101184;
    float s = c1g[o] * rsqrtf(c1v[o] + 1e-3f);
    ws[OFF_EPI1S + o] = s;
    ws[OFF_EPI1B + o] = s*(bc1[o] - c1m[o]) + c1b[o];
  } else if(idx < 101568){
    int o = idx - 101312;
    float s = c2g[o] * rsqrtf(c2v[o] + 1e-3f);
    ws[OFF_EPI2S + o] = s;
    ws[OFF_EPI2B + o] = s*(bc2[o] - c2m[o]) + c2b[o];
  } else if(idx < 101696){
    int o = idx - 101568;
    float s = c3g[o] * rsqrtf(c3v[o] + 1e-3f);
    ws[OFF_EPI3S + o] = s;
    ws[OFF_EPI3B + o] = s*(bc3[o] - c3m[o]) + c3b[o];
  }
}

// ---------------- encoder: conv1(1x8 SAME)+BN+GELU -> contract(256x32->64)+BN+GELU ----------------
// block = (b, 8-t tile); grid 1024 x 256 threads
__global__ __launch_bounds__(256) void encoder_kernel(
    const float* x, const float* w1f, const float* b1f,
    const float* s2e, const float* b2e, const float* we2, float* x_src)
{
  __shared__ float xs[15*32];     // rows t0-3 .. t0+11
  __shared__ float w1s[2048];
  __shared__ float b1s[256];
  __shared__ float aLDS[256*9];   // [(o_local*32+f)][u], stride 9 (bank-conflict pad)
  int blk = blockIdx.x; int b = blk>>5; int t0 = (blk&31)*8;
  int tid = threadIdx.x;
  for(int i=tid;i<2048;i+=256) w1s[i] = w1f[i];
  b1s[tid] = b1f[tid];
  for(int i=tid;i<480;i+=256){
    int r=i>>5, f=i&31; int t=t0-3+r;
    xs[i] = (t>=0 && t<256) ? x[(b*256+t)*32+f] : 0.f;
  }
  __syncthreads();
  int tl = tid & 7, e0 = tid >> 3;    // e0 in 0..31
  float acc0a=0.f, acc0b=0.f, acc1a=0.f, acc1b=0.f;
  for(int chunk=0;chunk<32;chunk++){
    int o = chunk*8 + (tid>>5); int f = tid & 31;
    float wv[8];
    #pragma unroll
    for(int j=0;j<8;j++) wv[j] = w1s[o*8+j];
    float bb = b1s[o];
    #pragma unroll
    for(int u=0;u<8;u++){
      float c = bb;
      #pragma unroll
      for(int j=0;j<8;j++) c = fmaf(wv[j], xs[(u+j)*32+f], c);
      aLDS[tid*9+u] = geluf(c);
    }
    __syncthreads();
    const float2* w2a = (const float2*)(we2 + (size_t)e0*8192 + chunk*256);
    const float2* w2b = (const float2*)(we2 + (size_t)(e0+32)*8192 + chunk*256);
    #pragma unroll 8
    for(int q=0;q<128;q++){
      float2 pa = w2a[q], pb = w2b[q];
      float a0 = aLDS[(2*q)*9 + tl];
      float a1 = aLDS[(2*q+1)*9 + tl];
      acc0a = fmaf(a0, pa.x, acc0a);
      acc0b = fmaf(a1, pa.y, acc0b);
      acc1a = fmaf(a0, pb.x, acc1a);
      acc1b = fmaf(a1, pb.y, acc1b);
    }
    __syncthreads();
  }
  int t = t0 + tl;
  float h0 = acc0a + acc0b, h1 = acc1a + acc1b;
  float v0 = geluf(s2e[e0]*h0 + b2e[e0]);
  float v1 = geluf(s2e[e0+32]*h1 + b2e[e0+32]);
  x_src[((size_t)(b*256+t))*64 + e0]      = v0;
  x_src[((size_t)(b*256+t))*64 + e0 + 32] = v1;
}

// ---------------- gates_x = x_src @ w_ih^T + bias ----------------
__global__ __launch_bounds__(256) void gates_kernel(
    const float* x_src, const float* wihT, const float* biasg, float* gx)
{
  __shared__ float xsh[32*64];
  int blk = blockIdx.x; int b = blk>>3, t0 = (blk&7)*32;
  int tid = threadIdx.x;
  for(int i=tid;i<2048;i+=256) xsh[i] = x_src[((size_t)b*256+t0)*64 + i];
  __syncthreads();
  int g0 = tid, g1 = tid + 256;
  float acc0[32], acc1[32];
  #pragma unroll
  for(int tt=0;tt<32;tt++){ acc0[tt]=0.f; acc1[tt]=0.f; }
  for(int e=0;e<64;e++){
    float w0 = wihT[e*512+g0], w1 = wihT[e*512+g1];
    #pragma unroll
    for(int tt=0;tt<32;tt++){
      float xv = xsh[tt*64+e];
      acc0[tt] = fmaf(xv, w0, acc0[tt]);
      acc1[tt] = fmaf(xv, w1, acc1[tt]);
    }
  }
  float bg0 = biasg[g0], bg1 = biasg[g1];
  #pragma unroll
  for(int tt=0;tt<32;tt++){
    gx[((size_t)b*256+t0+tt)*512 + g0] = acc0[tt] + bg0;
    gx[((size_t)b*256+t0+tt)*512 + g1] = acc1[tt] + bg1;
  }
}

// ---------------- LSTM: 32 blocks x 512 threads, w_hh^T register-resident ----------------
__global__ __launch_bounds__(512) void lstm_kernel(
    const float* gates_x, const float* whhT, float* hseq)
{
  __shared__ float hsh[128];
  __shared__ float gsh[512];
  int b = blockIdx.x, g = threadIdx.x;
  float w[128];
  #pragma unroll
  for(int k=0;k<128;k++) w[k] = whhT[k*512 + g];
  float c = 0.f;
  if(g < 128) hsh[g] = 0.f;
  __syncthreads();
  const float* gx = gates_x + (size_t)b*256*512;
  float gcur = gx[g];
  for(int t=0;t<256;t++){
    float gnext = (t < 255) ? gx[(size_t)(t+1)*512 + g] : 0.f;
    float a0=gcur, a1=0.f, a2=0.f, a3=0.f;
    #pragma unroll
    for(int k=0;k<128;k+=4){
      a0 = fmaf(hsh[k],   w[k],   a0);
      a1 = fmaf(hsh[k+1], w[k+1], a1);
      a2 = fmaf(hsh[k+2], w[k+2], a2);
      a3 = fmaf(hsh[k+3], w[k+3], a3);
    }
    gsh[g] = (a0+a1)+(a2+a3);
    __syncthreads();
    if(g < 128){
      float iv = sigmf(gsh[g]);
      float fv = sigmf(gsh[128+g]);
      float gv = tanhf(gsh[256+g]);
      float ov = sigmf(gsh[384+g]);
      c = fv*c + iv*gv;
      float h = ov*tanhf(c);
      hsh[g] = h;
      hseq[((size_t)b*256+t)*128 + g] = h;
    }
    __syncthreads();
    gcur = gnext;
  }
}

// ---------------- row-normalize hidden ----------------
__global__ __launch_bounds__(64) void hn_kernel(const float* hseq, float* hn)
{
  size_t row = blockIdx.x; int lane = threadIdx.x;
  const float* hp = hseq + row*128;
  float v0 = hp[lane], v1 = hp[lane+64];
  float ss = v0*v0 + v1*v1;
  #pragma unroll
  for(int m=1;m<64;m<<=1) ss += __shfl_xor(ss, m, 64);
  float r = 1.f / fmaxf(sqrtf(ss), 1e-8f);
  hn[row*128 + lane]      = v0*r;
  hn[row*128 + 64 + lane] = v1*r;
}

// ---------------- cluster: per-column partial/full sums of symmetric sim ----------------
// grid = 32 b x 8 col-chunks; thread = (col il, t-subrange ts)
__global__ __launch_bounds__(256) void pc_kernel(const float* hn, float* pcol, float* ccol)
{
  int blk = blockIdx.x; int b = blk>>3, chunk = blk&7;
  int tid = threadIdx.x; int il = tid & 31, ts = tid >> 5;
  int i = chunk*32 + il;
  const float4* hb = (const float4*)(hn + (size_t)b*32768);
  float4 hi[32];
  #pragma unroll
  for(int r=0;r<32;r++) hi[r] = hb[(size_t)i*32 + r];
  float ps=0.f, cs=0.f;
  for(int t=ts*32; t<ts*32+32; t++){
    float dx=0.f, dy=0.f, dz=0.f, dw=0.f;
    #pragma unroll
    for(int r=0;r<32;r++){
      float4 hv = hb[(size_t)t*32 + r];
      dx = fmaf(hi[r].x, hv.x, dx);
      dy = fmaf(hi[r].y, hv.y, dy);
      dz = fmaf(hi[r].z, hv.z, dz);
      dw = fmaf(hi[r].w, hv.w, dw);
    }
    float dot = (dx+dy)+(dz+dw);
    float sim = (t==i) ? 0.f : expf(-5.5f*(1.0f - dot));
    cs += sim;
    if(t < i) ps += sim;
  }
  __shared__ float red[16][32];
  red[ts][il] = ps; red[8+ts][il] = cs;
  __syncthreads();
  if(tid < 32){
    float s=0.f;
    for(int r=0;r<8;r++) s += red[r][tid];
    pcol[b*256 + chunk*32 + tid] = s;
  } else if(tid < 64){
    int c2 = tid - 32; float s=0.f;
    for(int r=0;r<8;r++) s += red[8+r][c2];
    ccol[b*256 + chunk*32 + c2] = s;
  }
}

// ---------------- prefix + dist + argmax + corr/last ----------------
__global__ __launch_bounds__(256) void cutcorr_kernel(
    const float* pcol, const float* ccol, const float* hseq,
    float* last, float* corr, int* cuts)
{
  int b = blockIdx.x, tid = threadIdx.x;
  __shared__ float D[256], RC[256], dist[256];
  __shared__ int cutsh;
  if(tid == 0){
    float d=0.f, r=0.f;
    for(int i=0;i<256;i++){
      d += 2.f*pcol[b*256+i]; D[i]=d;
      r += ccol[b*256+i];     RC[i]=r;
    }
  }
  __syncthreads();
  float tot = RC[255];
  if(tid < 255){
    float Dv = D[tid], Rv = RC[tid];
    float i_f = (float)(tid+1), j_f = 256.f - i_f;
    dist[tid] = Dv/(i_f*i_f) + (tot - 2.f*Rv + Dv)/(j_f*j_f) - 2.f*(Rv - Dv)/(i_f*j_f);
  }
  __syncthreads();
  if(tid == 0){
    float best = dist[0]; int bi = 0;
    for(int i=1;i<255;i++) if(dist[i] > best){ best = dist[i]; bi = i; }
    cutsh = bi + 1; cuts[b] = cutsh;
  }
  __syncthreads();
  int cut = cutsh;
  int k = tid & 127, half = tid >> 7;
  float s = 0.f;
  for(int t=half; t<cut; t+=2) s += hseq[((size_t)b*256+t)*128 + k];
  __shared__ float partial[2][128];
  partial[half][k] = s;
  __syncthreads();
  if(tid < 128){
    corr[b*128+tid] = (partial[0][tid] + partial[1][tid]) / (float)cut;
    last[b*128+tid] = hseq[((size_t)b*256+255)*128 + tid];
  }
}

// ---------------- KAN features: [x, sin(x),sin(2x),sin(4x), cos(x),cos(2x),cos(4x)] ----------------
__global__ __launch_bounds__(256) void feat_kernel(const float* xin, float* feat, int n)
{
  int idx = blockIdx.x*256 + threadIdx.x;
  if(idx >= n) return;
  float xv = xin[idx];
  float* fp = feat + (size_t)idx*7;
  fp[0]=xv;
  fp[1]=sinf(xv); fp[2]=sinf(2.f*xv); fp[3]=sinf(4.f*xv);
  fp[4]=cosf(xv); fp[5]=cosf(2.f*xv); fp[6]=cosf(4.f*xv);
}

// ---------------- generic KAN: block per output j, 32 batch accumulators ----------------
__global__ __launch_bounds__(256) void kan_kernel(
    const float* feat, const float* W1, const float* W2, const float* B1, const float* B2,
    int din, int dout, float* outp)
{
  int j = blockIdx.x, tid = threadIdx.x;
  int h = tid & 31, isub = tid >> 5;
  float acc[32];
  #pragma unroll
  for(int b=0;b<32;b++) acc[b]=0.f;
  float accB2 = 0.f;
  for(int i=isub; i<din; i+=8){
    size_t base = ((size_t)(i*dout + j))*32 + h;
    const float* w1p = W1 + base*7;
    float w1v[7];
    #pragma unroll
    for(int f=0;f<7;f++) w1v[f] = w1p[f];
    float b1v = B1[base];
    float w2v = W2[base];
    if(h == 0) accB2 += B2[i*dout + j];
    const float* fp0 = feat + (size_t)i*7;
    #pragma unroll 4
    for(int b=0;b<32;b++){
      const float* fp = fp0 + (size_t)b*din*7;
      float hv = b1v;
      #pragma unroll
      for(int f=0;f<7;f++) hv = fmaf(fp[f], w1v[f], hv);
      float sv = hv / (1.f + __expf(-hv));   // silu
      acc[b] = fmaf(sv, w2v, acc[b]);
    }
  }
  #pragma unroll
  for(int m=1;m<64;m<<=1){
    #pragma unroll
    for(int b=0;b<32;b++) acc[b] += __shfl_xor(acc[b], m, 64);
    accB2 += __shfl_xor(accB2, m, 64);
  }
  __shared__ float part[4][32];
  __shared__ float partB2[4];
  int lane = tid & 63, wv = tid >> 6;
  if(lane == 0){
    #pragma unroll
    for(int b=0;b<32;b++) part[wv][b] = acc[b];
    partB2[wv] = accB2;
  }
  __syncthreads();
  if(tid < 32){
    int b = tid;
    float r = part[0][b]+part[1][b]+part[2][b]+part[3][b]
            + partB2[0]+partB2[1]+partB2[2]+partB2[3];
    outp[b*dout + j] = r;
  }
}

// ---------------- z / x_z, x1 / x_all mixers ----------------
__global__ __launch_bounds__(256) void zmix_kernel(
    const float* muo, const float* stdo, const float* eps1, const float* last, float* xz)
{
  int idx = blockIdx.x*256 + threadIdx.x;
  if(idx >= 4096) return;
  int b = idx >> 7, k = idx & 127;
  float z = muo[idx] + softplusf(stdo[idx] - 5.f)*eps1[idx];
  xz[b*256 + k]       = last[idx];
  xz[b*256 + 128 + k] = z;
}

__global__ __launch_bounds__(256) void xall_kernel(
    const float* muco, const float* stdco, const float* eps2, const float* x2f, float* xa)
{
  int idx = blockIdx.x*256 + threadIdx.x;
  if(idx >= 4096) return;
  int b = idx >> 7, k = idx & 127;
  xa[b*256 + k]       = muco[idx] + softplusf(stdco[idx] - 5.f)*eps2[idx];
  xa[b*256 + 128 + k] = x2f[idx];
}

// ---------------- causal conv1d + folded BN + GELU ----------------
// grid (b, Cout/64); out[b][o][l]
__global__ __launch_bounds__(256) void conv_kernel(
    const float* xin, const float* w, const float* epi_s, const float* epi_b,
    float* out, int Cin, int Cout, int K)
{
  extern __shared__ float xsh[];
  int b = blockIdx.x, oc0 = blockIdx.y*64;
  int tid = threadIdx.x;
  for(int i=tid; i<Cin*32; i+=256) xsh[i] = xin[(size_t)b*Cin*32 + i];
  __syncthreads();
  int l = tid & 31, og = tid >> 5;
  for(int q=0;q<8;q++){
    int o = oc0 + og*8 + q;
    const float* wr = w + (size_t)o*Cin*K;
    float a0=0.f, a1=0.f;
    for(int c=0;c<Cin;c+=2){
      const float* w0 = wr + c*K;
      const float* w1 = wr + (c+1)*K;
      for(int k=0;k<K;k++){
        int li = l - (K-1) + k;
        if(li >= 0){
          a0 = fmaf(xsh[c*32 + li],     w0[k], a0);
          a1 = fmaf(xsh[(c+1)*32 + li], w1[k], a1);
        }
      }
    }
    float acc = a0 + a1;
    out[((size_t)b*Cout + o)*32 + l] = geluf(epi_s[o]*acc + epi_b[o]);
  }
}

// ---------------- squeeze-excite (in place) ----------------
__global__ __launch_bounds__(256) void se_kernel(
    float* xio, const float* w1, const float* w2, int C, int R)
{
  __shared__ float mean[256];
  __shared__ float y1[16];
  int b = blockIdx.x, tid = threadIdx.x;
  float* xb = xio + (size_t)b*C*32;
  if(tid < C){
    float s=0.f;
    for(int l=0;l<32;l++) s += xb[tid*32+l];
    mean[tid] = s*(1.f/32.f);
  }
  __syncthreads();
  if(tid < R){
    float s=0.f;
    for(int c=0;c<C;c++) s = fmaf(mean[c], w1[tid*C+c], s);
    y1[tid] = fmaxf(s, 0.f);
  }
  __syncthreads();
  if(tid < C){
    float s=0.f;
    for(int jj=0;jj<R;jj++) s = fmaf(y1[jj], w2[tid*R+jj], s);
    float sc = sigmf(s);
    for(int l=0;l<32;l++) xb[tid*32+l] *= sc;
  }
}

// ---------------- mean over l ----------------
__global__ __launch_bounds__(128) void mean_kernel(const float* xin, float* out)
{
  int b = blockIdx.x, c = threadIdx.x;
  float s = 0.f;
  for(int l=0;l<32;l++) s += xin[((size_t)b*128 + c)*32 + l];
  out[b*128 + c] = s*(1.f/32.f);
}

// ---------------- launch ----------------
extern "C" void kernel_launch(void* const* d_in, const int* in_sizes, int n_in,
                              void* d_out, int out_size, void* d_ws, size_t ws_size,
                              hipStream_t stream)
{
  const float* x    = (const float*)d_in[0];
  const float* we1  = (const float*)d_in[1];
  const float* be1  = (const float*)d_in[2];
  const float* e1g  = (const float*)d_in[3];
  const float* e1b  = (const float*)d_in[4];
  const float* e1m  = (const float*)d_in[5];
  const float* e1v  = (const float*)d_in[6];
  const float* we2  = (const float*)d_in[7];
  const float* be2  = (const float*)d_in[8];
  const float* e2g  = (const float*)d_in[9];
  const float* e2b  = (const float*)d_in[10];
  const float* e2m  = (const float*)d_in[11];
  const float* e2v  = (const float*)d_in[12];
  const float* wih  = (const float*)d_in[13];
  const float* whh  = (const float*)d_in[14];
  const float* bih  = (const float*)d_in[15];
  const float* bhh  = (const float*)d_in[16];
  const float* muW1 = (const float*)d_in[17];
  const float* muW2 = (const float*)d_in[18];
  const float* muB1 = (const float*)d_in[19];
  const float* muB2 = (const float*)d_in[20];
  const float* sdW1 = (const float*)d_in[21];
  const float* sdW2 = (const float*)d_in[22];
  const float* sdB1 = (const float*)d_in[23];
  const float* sdB2 = (const float*)d_in[24];
  const float* mcW1 = (const float*)d_in[25];
  const float* mcW2 = (const float*)d_in[26];
  const float* mcB1 = (const float*)d_in[27];
  const float* mcB2 = (const float*)d_in[28];
  const float* scW1 = (const float*)d_in[29];
  const float* scW2 = (const float*)d_in[30];
  const float* scB1 = (const float*)d_in[31];
  const float* scB2 = (const float*)d_in[32];
  const float* fcW1 = (const float*)d_in[33];
  const float* fcW2 = (const float*)d_in[34];
  const float* fcB1 = (const float*)d_in[35];
  const float* fcB2 = (const float*)d_in[36];
  const float* wc1  = (const float*)d_in[37];
  const float* bc1  = (const float*)d_in[38];
  const float* c1g  = (const float*)d_in[39];
  const float* c1b  = (const float*)d_in[40];
  const float* c1m  = (const float*)d_in[41];
  const float* c1v  = (const float*)d_in[42];
  const float* se1w1= (const float*)d_in[43];
  const float* se1w2= (const float*)d_in[44];
  const float* wc2  = (const float*)d_in[45];
  const float* bc2  = (const float*)d_in[46];
  const float* c2g  = (const float*)d_in[47];
  const float* c2b  = (const float*)d_in[48];
  const float* c2m  = (const float*)d_in[49];
  const float* c2v  = (const float*)d_in[50];
  const float* se2w1= (const float*)d_in[51];
  const float* se2w2= (const float*)d_in[52];
  const float* wc3  = (const float*)d_in[53];
  const float* bc3  = (const float*)d_in[54];
  const float* c3g  = (const float*)d_in[55];
  const float* c3b  = (const float*)d_in[56];
  const float* c3m  = (const float*)d_in[57];
  const float* c3v  = (const float*)d_in[58];
  const float* eps1 = (const float*)d_in[59];
  const float* eps2 = (const float*)d_in[60];

  float* ws = (float*)d_ws;

  prep_kernel<<<398, 256, 0, stream>>>(we1, be1, e1g,e1b,e1m,e1v,
      be2,e2g,e2b,e2m,e2v, wih,whh,bih,bhh,
      bc1,c1g,c1b,c1m,c1v, bc2,c2g,c2b,c2m,c2v, bc3,c3g,c3b,c3m,c3v, ws);

  encoder_kernel<<<1024, 256, 0, stream>>>(x, ws+OFF_W1F, ws+OFF_B1F,
      ws+OFF_S2E, ws+OFF_B2E, we2, ws+OFF_XSRC);

  gates_kernel<<<256, 256, 0, stream>>>(ws+OFF_XSRC, ws+OFF_WIHT, ws+OFF_BIASG, ws+OFF_GX);
  lstm_kernel<<<32, 512, 0, stream>>>(ws+OFF_GX, ws+OFF_WHHT, ws+OFF_HSEQ);

  hn_kernel<<<8192, 64, 0, stream>>>(ws+OFF_HSEQ, ws+OFF_HN);
  pc_kernel<<<256, 256, 0, stream>>>(ws+OFF_HN, ws+OFF_PCOL, ws+OFF_CCOL);
  cutcorr_kernel<<<32, 256, 0, stream>>>(ws+OFF_PCOL, ws+OFF_CCOL, ws+OFF_HSEQ,
      ws+OFF_LAST, ws+OFF_CORR, (int*)(ws+OFF_CUTS));

  feat_kernel<<<16, 256, 0, stream>>>(ws+OFF_CORR, ws+OFF_FEATA, 4096);
  kan_kernel<<<128, 256, 0, stream>>>(ws+OFF_FEATA, muW1, muW2, muB1, muB2, 128, 128, ws+OFF_MUO);
  kan_kernel<<<128, 256, 0, stream>>>(ws+OFF_FEATA, sdW1, sdW2, sdB1, sdB2, 128, 128, ws+OFF_STDO);
  zmix_kernel<<<16, 256, 0, stream>>>(ws+OFF_MUO, ws+OFF_STDO, eps1, ws+OFF_LAST, ws+OFF_XZ);
  feat_kernel<<<32, 256, 0, stream>>>(ws+OFF_XZ, ws+OFF_FEATB, 8192);
  kan_kernel<<<128, 256, 0, stream>>>(ws+OFF_FEATB, mcW1, mcW2, mcB1, mcB2, 256, 128, ws+OFF_MUCO);
  kan_kernel<<<128, 256, 0, stream>>>(ws+OFF_FEATB, scW1, scW2, scB1, scB2, 256, 128, ws+OFF_STDCO);

  conv_kernel<<<dim3(32,2), 256, 256*32*4, stream>>>(x, wc1, ws+OFF_EPI1S, ws+OFF_EPI1B, ws+OFF_XC1, 256, 128, 8);
  se_kernel<<<32, 256, 0, stream>>>(ws+OFF_XC1, se1w1, se1w2, 128, 8);
  conv_kernel<<<dim3(32,4), 256, 128*32*4, stream>>>(ws+OFF_XC1, wc2, ws+OFF_EPI2S, ws+OFF_EPI2B, ws+OFF_XC2, 128, 256, 5);
  se_kernel<<<32, 256, 0, stream>>>(ws+OFF_XC2, se2w1, se2w2, 256, 16);
  conv_kernel<<<dim3(32,2), 256, 256*32*4, stream>>>(ws+OFF_XC2, wc3, ws+OFF_EPI3S, ws+OFF_EPI3B, ws+OFF_XC3, 256, 128, 3);
  mean_kernel<<<32, 128, 0, stream>>>(ws+OFF_XC3, ws+OFF_X2F);

  xall_kernel<<<16, 256, 0, stream>>>(ws+OFF_MUCO, ws+OFF_STDCO, eps2, ws+OFF_X2F, ws+OFF_XALL);
  feat_kernel<<<32, 256, 0, stream>>>(ws+OFF_XALL, ws+OFF_FEATC, 8192);
  kan_kernel<<<10, 256, 0, stream>>>(ws+OFF_FEATC, fcW1, fcW2, fcB1, fcB2, 256, 10, (float*)d_out);
}

// Round 3
// 2611.899 us; speedup vs baseline: 1.5046x; 1.5046x over previous
//
#include <hip/hip_runtime.h>
#include <hip/hip_bf16.h>
#include <math.h>

#define DEV static __device__ __forceinline__

DEV float geluf(float x){ return 0.5f*x*(1.0f + erff(x*0.70710678118654752f)); }
DEV float sigmf(float x){ return 1.0f/(1.0f + __expf(-x)); }
DEV float softplusf(float x){ return (x > 15.f) ? x : log1pf(__expf(x)); }

// ---------------- workspace layout (float offsets) ----------------
enum : size_t {
  OFF_W1F   = 0,        // 2048  folded enc conv1 weights (256x8)
  OFF_B1F   = 2048,     // 256
  OFF_S2E   = 2304,     // 64
  OFF_B2E   = 2368,     // 64
  OFF_WIHT  = 2432,     // 32768 w_ih^T (64x512)
  OFF_BIASG = 35200,    // 512   b_ih+b_hh
  OFF_WHHT  = 35712,    // 65536 w_hh^T (128x512)
  OFF_EPI1S = 101248,   // 128
  OFF_EPI1B = 101376,   // 128
  OFF_EPI2S = 101504,   // 256
  OFF_EPI2B = 101760,   // 256
  OFF_EPI3S = 102016,   // 128
  OFF_EPI3B = 102144,   // 128
  OFF_XSRC  = 364416,   // 524288 (B,T,64)
  OFF_GX    = 888704,   // 4194304 (B,T,512)
  OFF_HSEQ  = 5083008,  // 1048576 (B,T,128)
  OFF_HN    = 6131584,  // 1048576
  OFF_PCOL  = 7180160,  // 8192
  OFF_CCOL  = 7188352,  // 8192
  OFF_CUTS  = 7196544,  // 32 (int)
  OFF_LAST  = 7196576,  // 4096
  OFF_CORR  = 7200672,  // 4096
  OFF_FEATA = 7204768,  // 28672 (B,128,7)
  OFF_MUO   = 7233440,  // 4096
  OFF_STDO  = 7237536,  // 4096
  OFF_XZ    = 7241632,  // 8192 (B,256)
  OFF_FEATB = 7249824,  // 57344 (B,256,7)
  OFF_MUCO  = 7307168,  // 4096
  OFF_STDCO = 7311264,  // 4096
  OFF_XC1   = 7315360,  // 131072 (B,128,32)
  OFF_XC2   = 7446432,  // 262144 (B,256,32)
  OFF_XC3   = 7708576,  // 131072
  OFF_X2F   = 7839648,  // 4096
  OFF_XALL  = 7843744,  // 8192
  OFF_FEATC = 7851936,  // 57344
  WS_FLOATS = 7909280   // ~31.6 MB
};

// ---------------- prep: fold BN, transpose LSTM weights ----------------
__global__ __launch_bounds__(256) void prep_kernel(
    const float* we1, const float* be1,
    const float* e1g, const float* e1b, const float* e1m, const float* e1v,
    const float* be2, const float* e2g, const float* e2b, const float* e2m, const float* e2v,
    const float* wih, const float* whh, const float* bih, const float* bhh,
    const float* bc1, const float* c1g, const float* c1b, const float* c1m, const float* c1v,
    const float* bc2, const float* c2g, const float* c2b, const float* c2m, const float* c2v,
    const float* bc3, const float* c3g, const float* c3b, const float* c3m, const float* c3v,
    float* ws)
{
  int idx = blockIdx.x*256 + threadIdx.x;
  if(idx < 2048){
    int o = idx>>3;
    float s = e1g[o] * rsqrtf(e1v[o] + 1e-5f);
    ws[OFF_W1F + idx] = we1[idx] * s;
  } else if(idx < 2304){
    int o = idx - 2048;
    float s = e1g[o] * rsqrtf(e1v[o] + 1e-5f);
    ws[OFF_B1F + o] = s*(be1[o] - e1m[o]) + e1b[o];
  } else if(idx < 2368){
    int e = idx - 2304;
    float s = e2g[e] * rsqrtf(e2v[e] + 1e-5f);
    ws[OFF_S2E + e] = s;
    ws[OFF_B2E + e] = s*(be2[e] - e2m[e]) + e2b[e];
  } else if(idx < 35136){
    int q = idx - 2368; int e = q>>9, g = q&511;
    ws[OFF_WIHT + q] = wih[g*64 + e];
  } else if(idx < 35648){
    int g = idx - 35136;
    ws[OFF_BIASG + g] = bih[g] + bhh[g];
  } else if(idx < 101184){
    int q = idx - 35648; int k = q>>9, g = q&511;
    ws[OFF_WHHT + q] = whh[g*128 + k];
  } else if(idx < 101312){
    int o = idx - 101184;
    float s = c1g[o] * rsqrtf(c1v[o] + 1e-3f);
    ws[OFF_EPI1S + o] = s;
    ws[OFF_EPI1B + o] = s*(bc1[o] - c1m[o]) + c1b[o];
  } else if(idx < 101568){
    int o = idx - 101312;
    float s = c2g[o] * rsqrtf(c2v[o] + 1e-3f);
    ws[OFF_EPI2S + o] = s;
    ws[OFF_EPI2B + o] = s*(bc2[o] - c2m[o]) + c2b[o];
  } else if(idx < 101696){
    int o = idx - 101568;
    float s = c3g[o] * rsqrtf(c3v[o] + 1e-3f);
    ws[OFF_EPI3S + o] = s;
    ws[OFF_EPI3B + o] = s*(bc3[o] - c3m[o]) + c3b[o];
  }
}

// ---------------- encoder: conv1(1x8 SAME)+BN+GELU -> contract(256x32->64)+BN+GELU ----------------
// block = (b, 8-t tile); grid 1024 x 256 threads
__global__ __launch_bounds__(256) void encoder_kernel(
    const float* x, const float* w1f, const float* b1f,
    const float* s2e, const float* b2e, const float* we2, float* x_src)
{
  __shared__ float xs[15*32];     // rows t0-3 .. t0+11
  __shared__ float w1s[2048];
  __shared__ float b1s[256];
  __shared__ float aLDS[256*9];   // [(o_local*32+f)][u], stride 9 (bank-conflict pad)
  int blk = blockIdx.x; int b = blk>>5; int t0 = (blk&31)*8;
  int tid = threadIdx.x;
  for(int i=tid;i<2048;i+=256) w1s[i] = w1f[i];
  b1s[tid] = b1f[tid];
  for(int i=tid;i<480;i+=256){
    int r=i>>5, f=i&31; int t=t0-3+r;
    xs[i] = (t>=0 && t<256) ? x[(b*256+t)*32+f] : 0.f;
  }
  __syncthreads();
  int tl = tid & 7, e0 = tid >> 3;    // e0 in 0..31
  float acc0a=0.f, acc0b=0.f, acc1a=0.f, acc1b=0.f;
  for(int chunk=0;chunk<32;chunk++){
    int o = chunk*8 + (tid>>5); int f = tid & 31;
    float wv[8];
    #pragma unroll
    for(int j=0;j<8;j++) wv[j] = w1s[o*8+j];
    float bb = b1s[o];
    #pragma unroll
    for(int u=0;u<8;u++){
      float c = bb;
      #pragma unroll
      for(int j=0;j<8;j++) c = fmaf(wv[j], xs[(u+j)*32+f], c);
      aLDS[tid*9+u] = geluf(c);
    }
    __syncthreads();
    const float2* w2a = (const float2*)(we2 + (size_t)e0*8192 + chunk*256);
    const float2* w2b = (const float2*)(we2 + (size_t)(e0+32)*8192 + chunk*256);
    #pragma unroll 8
    for(int q=0;q<128;q++){
      float2 pa = w2a[q], pb = w2b[q];
      float a0 = aLDS[(2*q)*9 + tl];
      float a1 = aLDS[(2*q+1)*9 + tl];
      acc0a = fmaf(a0, pa.x, acc0a);
      acc0b = fmaf(a1, pa.y, acc0b);
      acc1a = fmaf(a0, pb.x, acc1a);
      acc1b = fmaf(a1, pb.y, acc1b);
    }
    __syncthreads();
  }
  int t = t0 + tl;
  float h0 = acc0a + acc0b, h1 = acc1a + acc1b;
  float v0 = geluf(s2e[e0]*h0 + b2e[e0]);
  float v1 = geluf(s2e[e0+32]*h1 + b2e[e0+32]);
  x_src[((size_t)(b*256+t))*64 + e0]      = v0;
  x_src[((size_t)(b*256+t))*64 + e0 + 32] = v1;
}

// ---------------- gates_x = x_src @ w_ih^T + bias ----------------
__global__ __launch_bounds__(256) void gates_kernel(
    const float* x_src, const float* wihT, const float* biasg, float* gx)
{
  __shared__ float xsh[32*64];
  int blk = blockIdx.x; int b = blk>>3, t0 = (blk&7)*32;
  int tid = threadIdx.x;
  for(int i=tid;i<2048;i+=256) xsh[i] = x_src[((size_t)b*256+t0)*64 + i];
  __syncthreads();
  int g0 = tid, g1 = tid + 256;
  float acc0[32], acc1[32];
  #pragma unroll
  for(int tt=0;tt<32;tt++){ acc0[tt]=0.f; acc1[tt]=0.f; }
  for(int e=0;e<64;e++){
    float w0 = wihT[e*512+g0], w1 = wihT[e*512+g1];
    #pragma unroll
    for(int tt=0;tt<32;tt++){
      float xv = xsh[tt*64+e];
      acc0[tt] = fmaf(xv, w0, acc0[tt]);
      acc1[tt] = fmaf(xv, w1, acc1[tt]);
    }
  }
  float bg0 = biasg[g0], bg1 = biasg[g1];
  #pragma unroll
  for(int tt=0;tt<32;tt++){
    gx[((size_t)b*256+t0+tt)*512 + g0] = acc0[tt] + bg0;
    gx[((size_t)b*256+t0+tt)*512 + g1] = acc1[tt] + bg1;
  }
}

// ---------------- LSTM: 32 blocks x 512 threads, w_hh^T register-resident ----------------
__global__ __launch_bounds__(512) void lstm_kernel(
    const float* gates_x, const float* whhT, float* hseq)
{
  __shared__ float hsh[128];
  __shared__ float gsh[512];
  int b = blockIdx.x, g = threadIdx.x;
  float w[128];
  #pragma unroll
  for(int k=0;k<128;k++) w[k] = whhT[k*512 + g];
  float c = 0.f;
  if(g < 128) hsh[g] = 0.f;
  __syncthreads();
  const float* gx = gates_x + (size_t)b*256*512;
  float gcur = gx[g];
  for(int t=0;t<256;t++){
    float gnext = (t < 255) ? gx[(size_t)(t+1)*512 + g] : 0.f;
    float a0=gcur, a1=0.f, a2=0.f, a3=0.f;
    #pragma unroll
    for(int k=0;k<128;k+=4){
      a0 = fmaf(hsh[k],   w[k],   a0);
      a1 = fmaf(hsh[k+1], w[k+1], a1);
      a2 = fmaf(hsh[k+2], w[k+2], a2);
      a3 = fmaf(hsh[k+3], w[k+3], a3);
    }
    gsh[g] = (a0+a1)+(a2+a3);
    __syncthreads();
    if(g < 128){
      float iv = sigmf(gsh[g]);
      float fv = sigmf(gsh[128+g]);
      float gv = tanhf(gsh[256+g]);
      float ov = sigmf(gsh[384+g]);
      c = fv*c + iv*gv;
      float h = ov*tanhf(c);
      hsh[g] = h;
      hseq[((size_t)b*256+t)*128 + g] = h;
    }
    __syncthreads();
    gcur = gnext;
  }
}

// ---------------- row-normalize hidden ----------------
__global__ __launch_bounds__(64) void hn_kernel(const float* hseq, float* hn)
{
  size_t row = blockIdx.x; int lane = threadIdx.x;
  const float* hp = hseq + row*128;
  float v0 = hp[lane], v1 = hp[lane+64];
  float ss = v0*v0 + v1*v1;
  #pragma unroll
  for(int m=1;m<64;m<<=1) ss += __shfl_xor(ss, m, 64);
  float r = 1.f / fmaxf(sqrtf(ss), 1e-8f);
  hn[row*128 + lane]      = v0*r;
  hn[row*128 + 64 + lane] = v1*r;
}

// ---------------- cluster: per-column partial/full sums of symmetric sim ----------------
__global__ __launch_bounds__(256) void pc_kernel(const float* hn, float* pcol, float* ccol)
{
  int blk = blockIdx.x; int b = blk>>3, chunk = blk&7;
  int tid = threadIdx.x; int il = tid & 31, ts = tid >> 5;
  int i = chunk*32 + il;
  const float4* hb = (const float4*)(hn + (size_t)b*32768);
  float4 hi[32];
  #pragma unroll
  for(int r=0;r<32;r++) hi[r] = hb[(size_t)i*32 + r];
  float ps=0.f, cs=0.f;
  for(int t=ts*32; t<ts*32+32; t++){
    float dx=0.f, dy=0.f, dz=0.f, dw=0.f;
    #pragma unroll
    for(int r=0;r<32;r++){
      float4 hv = hb[(size_t)t*32 + r];
      dx = fmaf(hi[r].x, hv.x, dx);
      dy = fmaf(hi[r].y, hv.y, dy);
      dz = fmaf(hi[r].z, hv.z, dz);
      dw = fmaf(hi[r].w, hv.w, dw);
    }
    float dot = (dx+dy)+(dz+dw);
    float sim = (t==i) ? 0.f : expf(-5.5f*(1.0f - dot));
    cs += sim;
    if(t < i) ps += sim;
  }
  __shared__ float red[16][32];
  red[ts][il] = ps; red[8+ts][il] = cs;
  __syncthreads();
  if(tid < 32){
    float s=0.f;
    for(int r=0;r<8;r++) s += red[r][tid];
    pcol[b*256 + chunk*32 + tid] = s;
  } else if(tid < 64){
    int c2 = tid - 32; float s=0.f;
    for(int r=0;r<8;r++) s += red[8+r][c2];
    ccol[b*256 + chunk*32 + c2] = s;
  }
}

// ---------------- prefix + dist + argmax + corr/last ----------------
__global__ __launch_bounds__(256) void cutcorr_kernel(
    const float* pcol, const float* ccol, const float* hseq,
    float* last, float* corr, int* cuts)
{
  int b = blockIdx.x, tid = threadIdx.x;
  __shared__ float D[256], RC[256], dist[256];
  __shared__ int cutsh;
  if(tid == 0){
    float d=0.f, r=0.f;
    for(int i=0;i<256;i++){
      d += 2.f*pcol[b*256+i]; D[i]=d;
      r += ccol[b*256+i];     RC[i]=r;
    }
  }
  __syncthreads();
  float tot = RC[255];
  if(tid < 255){
    float Dv = D[tid], Rv = RC[tid];
    float i_f = (float)(tid+1), j_f = 256.f - i_f;
    dist[tid] = Dv/(i_f*i_f) + (tot - 2.f*Rv + Dv)/(j_f*j_f) - 2.f*(Rv - Dv)/(i_f*j_f);
  }
  __syncthreads();
  if(tid == 0){
    float best = dist[0]; int bi = 0;
    for(int i=1;i<255;i++) if(dist[i] > best){ best = dist[i]; bi = i; }
    cutsh = bi + 1; cuts[b] = cutsh;
  }
  __syncthreads();
  int cut = cutsh;
  int k = tid & 127, half = tid >> 7;
  float s = 0.f;
  for(int t=half; t<cut; t+=2) s += hseq[((size_t)b*256+t)*128 + k];
  __shared__ float partial[2][128];
  partial[half][k] = s;
  __syncthreads();
  if(tid < 128){
    corr[b*128+tid] = (partial[0][tid] + partial[1][tid]) / (float)cut;
    last[b*128+tid] = hseq[((size_t)b*256+255)*128 + tid];
  }
}

// ---------------- KAN features ----------------
__global__ __launch_bounds__(256) void feat_kernel(const float* xin, float* feat, int n)
{
  int idx = blockIdx.x*256 + threadIdx.x;
  if(idx >= n) return;
  float xv = xin[idx];
  float* fp = feat + (size_t)idx*7;
  fp[0]=xv;
  fp[1]=sinf(xv); fp[2]=sinf(2.f*xv); fp[3]=sinf(4.f*xv);
  fp[4]=cosf(xv); fp[5]=cosf(2.f*xv); fp[6]=cosf(4.f*xv);
}

// ---------------- generic KAN ----------------
__global__ __launch_bounds__(256) void kan_kernel(
    const float* feat, const float* W1, const float* W2, const float* B1, const float* B2,
    int din, int dout, float* outp)
{
  int j = blockIdx.x, tid = threadIdx.x;
  int h = tid & 31, isub = tid >> 5;
  float acc[32];
  #pragma unroll
  for(int b=0;b<32;b++) acc[b]=0.f;
  float accB2 = 0.f;
  for(int i=isub; i<din; i+=8){
    size_t base = ((size_t)(i*dout + j))*32 + h;
    const float* w1p = W1 + base*7;
    float w1v[7];
    #pragma unroll
    for(int f=0;f<7;f++) w1v[f] = w1p[f];
    float b1v = B1[base];
    float w2v = W2[base];
    if(h == 0) accB2 += B2[i*dout + j];
    const float* fp0 = feat + (size_t)i*7;
    #pragma unroll 4
    for(int b=0;b<32;b++){
      const float* fp = fp0 + (size_t)b*din*7;
      float hv = b1v;
      #pragma unroll
      for(int f=0;f<7;f++) hv = fmaf(fp[f], w1v[f], hv);
      float sv = hv / (1.f + __expf(-hv));   // silu
      acc[b] = fmaf(sv, w2v, acc[b]);
    }
  }
  #pragma unroll
  for(int m=1;m<64;m<<=1){
    #pragma unroll
    for(int b=0;b<32;b++) acc[b] += __shfl_xor(acc[b], m, 64);
    accB2 += __shfl_xor(accB2, m, 64);
  }
  __shared__ float part[4][32];
  __shared__ float partB2[4];
  int lane = tid & 63, wv = tid >> 6;
  if(lane == 0){
    #pragma unroll
    for(int b=0;b<32;b++) part[wv][b] = acc[b];
    partB2[wv] = accB2;
  }
  __syncthreads();
  if(tid < 32){
    int b = tid;
    float r = part[0][b]+part[1][b]+part[2][b]+part[3][b]
            + partB2[0]+partB2[1]+partB2[2]+partB2[3];
    outp[b*dout + j] = r;
  }
}

// ---------------- z / x_z, x1 / x_all mixers ----------------
__global__ __launch_bounds__(256) void zmix_kernel(
    const float* muo, const float* stdo, const float* eps1, const float* last, float* xz)
{
  int idx = blockIdx.x*256 + threadIdx.x;
  if(idx >= 4096) return;
  int b = idx >> 7, k = idx & 127;
  float z = muo[idx] + softplusf(stdo[idx] - 5.f)*eps1[idx];
  xz[b*256 + k]       = last[idx];
  xz[b*256 + 128 + k] = z;
}

__global__ __launch_bounds__(256) void xall_kernel(
    const float* muco, const float* stdco, const float* eps2, const float* x2f, float* xa)
{
  int idx = blockIdx.x*256 + threadIdx.x;
  if(idx >= 4096) return;
  int b = idx >> 7, k = idx & 127;
  xa[b*256 + k]       = muco[idx] + softplusf(stdco[idx] - 5.f)*eps2[idx];
  xa[b*256 + 128 + k] = x2f[idx];
}

// ---------------- causal conv1d + folded BN + GELU (templated, LDS-staged weights) ----------------
// block: (b, 8 output channels); 256 threads = (og=tid>>5 in 0..7, l=tid&31)
template<int CIN, int K>
__global__ __launch_bounds__(256) void conv_t_kernel(
    const float* __restrict__ xin, const float* __restrict__ w,
    const float* __restrict__ epi_s, const float* __restrict__ epi_b,
    float* __restrict__ out, int Cout)
{
  __shared__ float xsh[CIN*32];
  __shared__ float wsh[8*CIN*K];
  int b = blockIdx.x, oc0 = blockIdx.y*8;
  int tid = threadIdx.x;
  {
    const float4* xsrc = (const float4*)(xin + (size_t)b*CIN*32);
    #pragma unroll 2
    for(int i=tid; i<CIN*8; i+=256) ((float4*)xsh)[i] = xsrc[i];
    const float4* wsrc = (const float4*)(w + (size_t)oc0*CIN*K);
    #pragma unroll 4
    for(int i=tid; i<(8*CIN*K)/4; i+=256) ((float4*)wsh)[i] = wsrc[i];
  }
  __syncthreads();
  int l = tid & 31, og = tid >> 5;
  const float* wr = wsh + og*CIN*K;
  float acc = 0.f;
  #pragma unroll 4
  for(int c=0;c<CIN;c++){
    const float* xr = xsh + c*32 + l - (K-1);
    const float* wc = wr + c*K;
    #pragma unroll
    for(int k=0;k<K;k++){
      if(l - (K-1) + k >= 0) acc = fmaf(xr[k], wc[k], acc);
    }
  }
  int o = oc0 + og;
  out[((size_t)b*Cout + o)*32 + l] = geluf(epi_s[o]*acc + epi_b[o]);
}

// ---------------- squeeze-excite (in place) ----------------
__global__ __launch_bounds__(256) void se_kernel(
    float* xio, const float* w1, const float* w2, int C, int R)
{
  __shared__ float mean[256];
  __shared__ float y1[16];
  int b = blockIdx.x, tid = threadIdx.x;
  float* xb = xio + (size_t)b*C*32;
  if(tid < C){
    float s=0.f;
    for(int l=0;l<32;l++) s += xb[tid*32+l];
    mean[tid] = s*(1.f/32.f);
  }
  __syncthreads();
  if(tid < R){
    float s=0.f;
    for(int c=0;c<C;c++) s = fmaf(mean[c], w1[tid*C+c], s);
    y1[tid] = fmaxf(s, 0.f);
  }
  __syncthreads();
  if(tid < C){
    float s=0.f;
    for(int jj=0;jj<R;jj++) s = fmaf(y1[jj], w2[tid*R+jj], s);
    float sc = sigmf(s);
    for(int l=0;l<32;l++) xb[tid*32+l] *= sc;
  }
}

// ---------------- mean over l ----------------
__global__ __launch_bounds__(128) void mean_kernel(const float* xin, float* out)
{
  int b = blockIdx.x, c = threadIdx.x;
  float s = 0.f;
  for(int l=0;l<32;l++) s += xin[((size_t)b*128 + c)*32 + l];
  out[b*128 + c] = s*(1.f/32.f);
}

// ---------------- launch ----------------
extern "C" void kernel_launch(void* const* d_in, const int* in_sizes, int n_in,
                              void* d_out, int out_size, void* d_ws, size_t ws_size,
                              hipStream_t stream)
{
  const float* x    = (const float*)d_in[0];
  const float* we1  = (const float*)d_in[1];
  const float* be1  = (const float*)d_in[2];
  const float* e1g  = (const float*)d_in[3];
  const float* e1b  = (const float*)d_in[4];
  const float* e1m  = (const float*)d_in[5];
  const float* e1v  = (const float*)d_in[6];
  const float* we2  = (const float*)d_in[7];
  const float* be2  = (const float*)d_in[8];
  const float* e2g  = (const float*)d_in[9];
  const float* e2b  = (const float*)d_in[10];
  const float* e2m  = (const float*)d_in[11];
  const float* e2v  = (const float*)d_in[12];
  const float* wih  = (const float*)d_in[13];
  const float* whh  = (const float*)d_in[14];
  const float* bih  = (const float*)d_in[15];
  const float* bhh  = (const float*)d_in[16];
  const float* muW1 = (const float*)d_in[17];
  const float* muW2 = (const float*)d_in[18];
  const float* muB1 = (const float*)d_in[19];
  const float* muB2 = (const float*)d_in[20];
  const float* sdW1 = (const float*)d_in[21];
  const float* sdW2 = (const float*)d_in[22];
  const float* sdB1 = (const float*)d_in[23];
  const float* sdB2 = (const float*)d_in[24];
  const float* mcW1 = (const float*)d_in[25];
  const float* mcW2 = (const float*)d_in[26];
  const float* mcB1 = (const float*)d_in[27];
  const float* mcB2 = (const float*)d_in[28];
  const float* scW1 = (const float*)d_in[29];
  const float* scW2 = (const float*)d_in[30];
  const float* scB1 = (const float*)d_in[31];
  const float* scB2 = (const float*)d_in[32];
  const float* fcW1 = (const float*)d_in[33];
  const float* fcW2 = (const float*)d_in[34];
  const float* fcB1 = (const float*)d_in[35];
  const float* fcB2 = (const float*)d_in[36];
  const float* wc1  = (const float*)d_in[37];
  const float* bc1  = (const float*)d_in[38];
  const float* c1g  = (const float*)d_in[39];
  const float* c1b  = (const float*)d_in[40];
  const float* c1m  = (const float*)d_in[41];
  const float* c1v  = (const float*)d_in[42];
  const float* se1w1= (const float*)d_in[43];
  const float* se1w2= (const float*)d_in[44];
  const float* wc2  = (const float*)d_in[45];
  const float* bc2  = (const float*)d_in[46];
  const float* c2g  = (const float*)d_in[47];
  const float* c2b  = (const float*)d_in[48];
  const float* c2m  = (const float*)d_in[49];
  const float* c2v  = (const float*)d_in[50];
  const float* se2w1= (const float*)d_in[51];
  const float* se2w2= (const float*)d_in[52];
  const float* wc3  = (const float*)d_in[53];
  const float* bc3  = (const float*)d_in[54];
  const float* c3g  = (const float*)d_in[55];
  const float* c3b  = (const float*)d_in[56];
  const float* c3m  = (const float*)d_in[57];
  const float* c3v  = (const float*)d_in[58];
  const float* eps1 = (const float*)d_in[59];
  const float* eps2 = (const float*)d_in[60];

  float* ws = (float*)d_ws;

  prep_kernel<<<398, 256, 0, stream>>>(we1, be1, e1g,e1b,e1m,e1v,
      be2,e2g,e2b,e2m,e2v, wih,whh,bih,bhh,
      bc1,c1g,c1b,c1m,c1v, bc2,c2g,c2b,c2m,c2v, bc3,c3g,c3b,c3m,c3v, ws);

  encoder_kernel<<<1024, 256, 0, stream>>>(x, ws+OFF_W1F, ws+OFF_B1F,
      ws+OFF_S2E, ws+OFF_B2E, we2, ws+OFF_XSRC);

  gates_kernel<<<256, 256, 0, stream>>>(ws+OFF_XSRC, ws+OFF_WIHT, ws+OFF_BIASG, ws+OFF_GX);
  lstm_kernel<<<32, 512, 0, stream>>>(ws+OFF_GX, ws+OFF_WHHT, ws+OFF_HSEQ);

  hn_kernel<<<8192, 64, 0, stream>>>(ws+OFF_HSEQ, ws+OFF_HN);
  pc_kernel<<<256, 256, 0, stream>>>(ws+OFF_HN, ws+OFF_PCOL, ws+OFF_CCOL);
  cutcorr_kernel<<<32, 256, 0, stream>>>(ws+OFF_PCOL, ws+OFF_CCOL, ws+OFF_HSEQ,
      ws+OFF_LAST, ws+OFF_CORR, (int*)(ws+OFF_CUTS));

  feat_kernel<<<16, 256, 0, stream>>>(ws+OFF_CORR, ws+OFF_FEATA, 4096);
  kan_kernel<<<128, 256, 0, stream>>>(ws+OFF_FEATA, muW1, muW2, muB1, muB2, 128, 128, ws+OFF_MUO);
  kan_kernel<<<128, 256, 0, stream>>>(ws+OFF_FEATA, sdW1, sdW2, sdB1, sdB2, 128, 128, ws+OFF_STDO);
  zmix_kernel<<<16, 256, 0, stream>>>(ws+OFF_MUO, ws+OFF_STDO, eps1, ws+OFF_LAST, ws+OFF_XZ);
  feat_kernel<<<32, 256, 0, stream>>>(ws+OFF_XZ, ws+OFF_FEATB, 8192);
  kan_kernel<<<128, 256, 0, stream>>>(ws+OFF_FEATB, mcW1, mcW2, mcB1, mcB2, 256, 128, ws+OFF_MUCO);
  kan_kernel<<<128, 256, 0, stream>>>(ws+OFF_FEATB, scW1, scW2, scB1, scB2, 256, 128, ws+OFF_STDCO);

  conv_t_kernel<256,8><<<dim3(32,16), 256, 0, stream>>>(x, wc1, ws+OFF_EPI1S, ws+OFF_EPI1B, ws+OFF_XC1, 128);
  se_kernel<<<32, 256, 0, stream>>>(ws+OFF_XC1, se1w1, se1w2, 128, 8);
  conv_t_kernel<128,5><<<dim3(32,32), 256, 0, stream>>>(ws+OFF_XC1, wc2, ws+OFF_EPI2S, ws+OFF_EPI2B, ws+OFF_XC2, 256);
  se_kernel<<<32, 256, 0, stream>>>(ws+OFF_XC2, se2w1, se2w2, 256, 16);
  conv_t_kernel<256,3><<<dim3(32,16), 256, 0, stream>>>(ws+OFF_XC2, wc3, ws+OFF_EPI3S, ws+OFF_EPI3B, ws+OFF_XC3, 128);
  mean_kernel<<<32, 128, 0, stream>>>(ws+OFF_XC3, ws+OFF_X2F);

  xall_kernel<<<16, 256, 0, stream>>>(ws+OFF_MUCO, ws+OFF_STDCO, eps2, ws+OFF_X2F, ws+OFF_XALL);
  feat_kernel<<<32, 256, 0, stream>>>(ws+OFF_XALL, ws+OFF_FEATC, 8192);
  kan_kernel<<<10, 256, 0, stream>>>(ws+OFF_FEATC, fcW1, fcW2, fcB1, fcB2, 256, 10, (float*)d_out);
}

// Round 4
// 2307.342 us; speedup vs baseline: 1.7032x; 1.1320x over previous
//
#include <hip/hip_runtime.h>
#include <hip/hip_bf16.h>
#include <math.h>

typedef __hip_bfloat16 bf16;

#define DEV static __device__ __forceinline__

DEV float geluf(float x){ return 0.5f*x*(1.0f + erff(x*0.70710678118654752f)); }
DEV float sigmf(float x){ return 1.0f/(1.0f + __expf(-x)); }
DEV float softplusf(float x){ return (x > 15.f) ? x : log1pf(__expf(x)); }
DEV float tanhfast(float x){ float e = __expf(2.f*x); return fmaf(-2.f, 1.f/(e+1.f), 1.f); }

typedef __attribute__((ext_vector_type(8))) short v8s;   // 8 bf16 (4 VGPRs)
typedef __attribute__((ext_vector_type(4))) float v4f;   // 4 fp32 acc

// ---------------- workspace layout (float offsets) ----------------
enum : size_t {
  OFF_W1F   = 0,        // 2048  folded enc conv1 weights (256x8)
  OFF_B1F   = 2048,     // 256
  OFF_S2E   = 2304,     // 64
  OFF_B2E   = 2368,     // 64
  OFF_WIHT  = 2432,     // 32768 w_ih^T (64x512)
  OFF_BIASG = 35200,    // 512   b_ih+b_hh
  OFF_WHHT  = 35712,    // 65536 w_hh^T (128x512)
  OFF_EPI1S = 101248,   // 128
  OFF_EPI1B = 101376,   // 128
  OFF_EPI2S = 101504,   // 256
  OFF_EPI2B = 101760,   // 256
  OFF_EPI3S = 102016,   // 128
  OFF_EPI3B = 102144,   // 128
  OFF_WE2B  = 102272,   // 262144 floats = 524288 bf16: we2 repacked [o][e][f]
  OFF_XSRC  = 364416,   // 524288 (B,T,64)
  OFF_GX    = 888704,   // 4194304 (B,T,512)
  OFF_HSEQ  = 5083008,  // 1048576 (B,T,128)
  OFF_HN    = 6131584,  // 1048576
  OFF_PCOL  = 7180160,  // 8192
  OFF_CCOL  = 7188352,  // 8192
  OFF_CUTS  = 7196544,  // 32 (int)
  OFF_LAST  = 7196576,  // 4096
  OFF_CORR  = 7200672,  // 4096
  OFF_FEATA = 7204768,  // 28672 (B,128,7)
  OFF_MUO   = 7233440,  // 4096
  OFF_STDO  = 7237536,  // 4096
  OFF_XZ    = 7241632,  // 8192 (B,256)
  OFF_FEATB = 7249824,  // 57344 (B,256,7)
  OFF_MUCO  = 7307168,  // 4096
  OFF_STDCO = 7311264,  // 4096
  OFF_XC1   = 7315360,  // 131072 (B,128,32)
  OFF_XC2   = 7446432,  // 262144 (B,256,32)
  OFF_XC3   = 7708576,  // 131072
  OFF_X2F   = 7839648,  // 4096
  OFF_XALL  = 7843744,  // 8192
  OFF_FEATC = 7851936,  // 57344
  WS_FLOATS = 7909280   // ~31.6 MB
};

// ---------------- prep: fold BN, transpose LSTM weights, repack we2 ----------------
__global__ __launch_bounds__(256) void prep_kernel(
    const float* we1, const float* be1,
    const float* e1g, const float* e1b, const float* e1m, const float* e1v,
    const float* we2, const float* be2, const float* e2g, const float* e2b, const float* e2m, const float* e2v,
    const float* wih, const float* whh, const float* bih, const float* bhh,
    const float* bc1, const float* c1g, const float* c1b, const float* c1m, const float* c1v,
    const float* bc2, const float* c2g, const float* c2b, const float* c2m, const float* c2v,
    const float* bc3, const float* c3g, const float* c3b, const float* c3m, const float* c3v,
    float* ws)
{
  int idx = blockIdx.x*256 + threadIdx.x;
  if(idx < 2048){
    int o = idx>>3;
    float s = e1g[o] * rsqrtf(e1v[o] + 1e-5f);
    ws[OFF_W1F + idx] = we1[idx] * s;
  } else if(idx < 2304){
    int o = idx - 2048;
    float s = e1g[o] * rsqrtf(e1v[o] + 1e-5f);
    ws[OFF_B1F + o] = s*(be1[o] - e1m[o]) + e1b[o];
  } else if(idx < 2368){
    int e = idx - 2304;
    float s = e2g[e] * rsqrtf(e2v[e] + 1e-5f);
    ws[OFF_S2E + e] = s;
    ws[OFF_B2E + e] = s*(be2[e] - e2m[e]) + e2b[e];
  } else if(idx < 35136){
    int q = idx - 2368; int e = q>>9, g = q&511;
    ws[OFF_WIHT + q] = wih[g*64 + e];
  } else if(idx < 35648){
    int g = idx - 35136;
    ws[OFF_BIASG + g] = bih[g] + bhh[g];
  } else if(idx < 101184){
    int q = idx - 35648; int k = q>>9, g = q&511;
    ws[OFF_WHHT + q] = whh[g*128 + k];
  } else if(idx < 101312){
    int o = idx - 101184;
    float s = c1g[o] * rsqrtf(c1v[o] + 1e-3f);
    ws[OFF_EPI1S + o] = s;
    ws[OFF_EPI1B + o] = s*(bc1[o] - c1m[o]) + c1b[o];
  } else if(idx < 101568){
    int o = idx - 101312;
    float s = c2g[o] * rsqrtf(c2v[o] + 1e-3f);
    ws[OFF_EPI2S + o] = s;
    ws[OFF_EPI2B + o] = s*(bc2[o] - c2m[o]) + c2b[o];
  } else if(idx < 101696){
    int o = idx - 101568;
    float s = c3g[o] * rsqrtf(c3v[o] + 1e-3f);
    ws[OFF_EPI3S + o] = s;
    ws[OFF_EPI3B + o] = s*(bc3[o] - c3m[o]) + c3b[o];
  } else if(idx < 625984){
    // we2 repack: [e][o*32+f] f32 -> [o][e][f] bf16
    int q = idx - 101696;
    int o = q >> 11, rem = q & 2047;
    int e = rem >> 5, f = rem & 31;
    bf16* Wr = (bf16*)(ws + OFF_WE2B);
    Wr[q] = __float2bfloat16(we2[(size_t)e*8192 + o*32 + f]);
  }
}

// ---------------- encoder: conv1(1x8 SAME)+BN+GELU fused into bf16 MFMA GEMM ----------------
// grid 256 = (b 32) x (tg 8); M-tile = 32 t, N = 64 e, K = 256 o x 32 f
__global__ __launch_bounds__(256) void encoder_kernel(
    const float* __restrict__ x, const float* __restrict__ w1f, const float* __restrict__ b1f,
    const float* __restrict__ s2e, const float* __restrict__ b2e,
    const bf16* __restrict__ Wr, float* __restrict__ x_src)
{
  __shared__ float xs[39*32];          // rows t0-3 .. t0+35
  __shared__ float w1s[2048];
  __shared__ float b1s[256];
  __shared__ unsigned short At[2][32*40];   // A tile bf16, row stride 40 (pad)
  __shared__ unsigned short Bt[2][64*40];   // B tile bf16, row stride 40 (pad)

  int blk = blockIdx.x; int b = blk>>3; int t0 = (blk&7)*32;
  int tid = threadIdx.x;

  for(int i=tid;i<2048;i+=256) w1s[i] = w1f[i];
  b1s[tid] = b1f[tid];
  for(int i=tid;i<39*32;i+=256){
    int r=i>>5, f=i&31; int t=t0-3+r;
    xs[i] = (t>=0 && t<256) ? x[(b*256+t)*32+f] : 0.f;
  }
  __syncthreads();

  int f   = tid & 31, tq = tid >> 5;        // conv-staging role
  int lane = tid & 63, w = tid >> 6;        // mfma role
  int wm = w & 1, wn = w >> 1;
  int m0 = wm*16, n0 = wn*32;
  int l15 = lane & 15, quad = lane >> 4;
  int a_off  = (m0 + l15)*40 + quad*8;
  int b_off0 = (n0 + l15)*40 + quad*8;
  int b_off1 = b_off0 + 16*40;

  const v8s* Wv = (const v8s*)Wr;           // 16B per entry, [o*256 + tid]
  int be_ = tid >> 2, bf_ = (tid & 3)*8;

  // stage o = 0 into buffer 0
  {
    v8s wv8 = Wv[tid];
    *(v8s*)&Bt[0][be_*40 + bf_] = wv8;
    float wv[8];
    #pragma unroll
    for(int j=0;j<8;j++) wv[j] = w1s[j];
    float bb = b1s[0];
    #pragma unroll
    for(int i=0;i<4;i++){
      int tl = tq*4 + i;
      float c = bb;
      #pragma unroll
      for(int j=0;j<8;j++) c = fmaf(wv[j], xs[(tl+j)*32+f], c);
      At[0][tl*40+f] = ((__hip_bfloat16_raw)__float2bfloat16(geluf(c))).x;
    }
  }
  __syncthreads();

  v4f acc0 = {0.f,0.f,0.f,0.f}, acc1 = {0.f,0.f,0.f,0.f};

  for(int o=0;o<256;o++){
    int p = o & 1, q = p ^ 1;
    if(o < 255){
      int on = o + 1;
      v8s wv8 = Wv[on*256 + tid];
      *(v8s*)&Bt[q][be_*40 + bf_] = wv8;
      float wv[8];
      #pragma unroll
      for(int j=0;j<8;j++) wv[j] = w1s[on*8+j];
      float bb = b1s[on];
      #pragma unroll
      for(int i=0;i<4;i++){
        int tl = tq*4 + i;
        float c = bb;
        #pragma unroll
        for(int j=0;j<8;j++) c = fmaf(wv[j], xs[(tl+j)*32+f], c);
        At[q][tl*40+f] = ((__hip_bfloat16_raw)__float2bfloat16(geluf(c))).x;
      }
    }
    v8s av  = *(const v8s*)&At[p][a_off];
    v8s bv0 = *(const v8s*)&Bt[p][b_off0];
    v8s bv1 = *(const v8s*)&Bt[p][b_off1];
    acc0 = __builtin_amdgcn_mfma_f32_16x16x32_bf16(av, bv0, acc0, 0, 0, 0);
    acc1 = __builtin_amdgcn_mfma_f32_16x16x32_bf16(av, bv1, acc1, 0, 0, 0);
    __syncthreads();
  }

  // epilogue: D row = quad*4+reg (m), col = l15 (n)
  #pragma unroll
  for(int r=0;r<4;r++){
    int t = t0 + m0 + quad*4 + r;
    int e0 = n0 + l15;
    float v0 = geluf(s2e[e0]*acc0[r] + b2e[e0]);
    x_src[((size_t)(b*256+t))*64 + e0] = v0;
    int e1 = e0 + 16;
    float v1 = geluf(s2e[e1]*acc1[r] + b2e[e1]);
    x_src[((size_t)(b*256+t))*64 + e1] = v1;
  }
}

// ---------------- gates_x = x_src @ w_ih^T + bias ----------------
__global__ __launch_bounds__(256) void gates_kernel(
    const float* x_src, const float* wihT, const float* biasg, float* gx)
{
  __shared__ float xsh[32*64];
  int blk = blockIdx.x; int b = blk>>3, t0 = (blk&7)*32;
  int tid = threadIdx.x;
  for(int i=tid;i<2048;i+=256) xsh[i] = x_src[((size_t)b*256+t0)*64 + i];
  __syncthreads();
  int g0 = tid, g1 = tid + 256;
  float acc0[32], acc1[32];
  #pragma unroll
  for(int tt=0;tt<32;tt++){ acc0[tt]=0.f; acc1[tt]=0.f; }
  for(int e=0;e<64;e++){
    float w0 = wihT[e*512+g0], w1 = wihT[e*512+g1];
    #pragma unroll
    for(int tt=0;tt<32;tt++){
      float xv = xsh[tt*64+e];
      acc0[tt] = fmaf(xv, w0, acc0[tt]);
      acc1[tt] = fmaf(xv, w1, acc1[tt]);
    }
  }
  float bg0 = biasg[g0], bg1 = biasg[g1];
  #pragma unroll
  for(int tt=0;tt<32;tt++){
    gx[((size_t)b*256+t0+tt)*512 + g0] = acc0[tt] + bg0;
    gx[((size_t)b*256+t0+tt)*512 + g1] = acc1[tt] + bg1;
  }
}

// ---------------- LSTM: 32 blocks x 512 threads, w_hh^T register-resident ----------------
__global__ __launch_bounds__(512) void lstm_kernel(
    const float* gates_x, const float* whhT, float* hseq)
{
  __shared__ float hsh[128];
  __shared__ float gsh[512];
  int b = blockIdx.x, g = threadIdx.x;
  float w[128];
  #pragma unroll
  for(int k=0;k<128;k++) w[k] = whhT[k*512 + g];
  float c = 0.f;
  if(g < 128) hsh[g] = 0.f;
  __syncthreads();
  const float* gx = gates_x + (size_t)b*256*512;
  const float4* hs4 = (const float4*)hsh;
  float gcur = gx[g];
  for(int t=0;t<256;t++){
    float gnext = (t < 255) ? gx[(size_t)(t+1)*512 + g] : 0.f;
    float a0=gcur, a1=0.f, a2=0.f, a3=0.f;
    #pragma unroll
    for(int kk=0;kk<32;kk++){
      float4 hv = hs4[kk];
      a0 = fmaf(hv.x, w[4*kk],   a0);
      a1 = fmaf(hv.y, w[4*kk+1], a1);
      a2 = fmaf(hv.z, w[4*kk+2], a2);
      a3 = fmaf(hv.w, w[4*kk+3], a3);
    }
    gsh[g] = (a0+a1)+(a2+a3);
    __syncthreads();
    if(g < 128){
      float iv = sigmf(gsh[g]);
      float fv = sigmf(gsh[128+g]);
      float gv = tanhfast(gsh[256+g]);
      float ov = sigmf(gsh[384+g]);
      c = fv*c + iv*gv;
      float h = ov*tanhfast(c);
      hsh[g] = h;
      hseq[((size_t)b*256+t)*128 + g] = h;
    }
    __syncthreads();
    gcur = gnext;
  }
}

// ---------------- row-normalize hidden ----------------
__global__ __launch_bounds__(64) void hn_kernel(const float* hseq, float* hn)
{
  size_t row = blockIdx.x; int lane = threadIdx.x;
  const float* hp = hseq + row*128;
  float v0 = hp[lane], v1 = hp[lane+64];
  float ss = v0*v0 + v1*v1;
  #pragma unroll
  for(int m=1;m<64;m<<=1) ss += __shfl_xor(ss, m, 64);
  float r = 1.f / fmaxf(sqrtf(ss), 1e-8f);
  hn[row*128 + lane]      = v0*r;
  hn[row*128 + 64 + lane] = v1*r;
}

// ---------------- cluster: per-column partial/full sums of symmetric sim ----------------
__global__ __launch_bounds__(256) void pc_kernel(const float* hn, float* pcol, float* ccol)
{
  int blk = blockIdx.x; int b = blk>>3, chunk = blk&7;
  int tid = threadIdx.x; int il = tid & 31, ts = tid >> 5;
  int i = chunk*32 + il;
  const float4* hb = (const float4*)(hn + (size_t)b*32768);
  float4 hi[32];
  #pragma unroll
  for(int r=0;r<32;r++) hi[r] = hb[(size_t)i*32 + r];
  float ps=0.f, cs=0.f;
  for(int t=ts*32; t<ts*32+32; t++){
    float dx=0.f, dy=0.f, dz=0.f, dw=0.f;
    #pragma unroll
    for(int r=0;r<32;r++){
      float4 hv = hb[(size_t)t*32 + r];
      dx = fmaf(hi[r].x, hv.x, dx);
      dy = fmaf(hi[r].y, hv.y, dy);
      dz = fmaf(hi[r].z, hv.z, dz);
      dw = fmaf(hi[r].w, hv.w, dw);
    }
    float dot = (dx+dy)+(dz+dw);
    float sim = (t==i) ? 0.f : expf(-5.5f*(1.0f - dot));
    cs += sim;
    if(t < i) ps += sim;
  }
  __shared__ float red[16][32];
  red[ts][il] = ps; red[8+ts][il] = cs;
  __syncthreads();
  if(tid < 32){
    float s=0.f;
    for(int r=0;r<8;r++) s += red[r][tid];
    pcol[b*256 + chunk*32 + tid] = s;
  } else if(tid < 64){
    int c2 = tid - 32; float s=0.f;
    for(int r=0;r<8;r++) s += red[8+r][c2];
    ccol[b*256 + chunk*32 + c2] = s;
  }
}

// ---------------- prefix + dist + argmax + corr/last ----------------
__global__ __launch_bounds__(256) void cutcorr_kernel(
    const float* pcol, const float* ccol, const float* hseq,
    float* last, float* corr, int* cuts)
{
  int b = blockIdx.x, tid = threadIdx.x;
  __shared__ float D[256], RC[256], dist[256];
  __shared__ int cutsh;
  if(tid == 0){
    float d=0.f, r=0.f;
    for(int i=0;i<256;i++){
      d += 2.f*pcol[b*256+i]; D[i]=d;
      r += ccol[b*256+i];     RC[i]=r;
    }
  }
  __syncthreads();
  float tot = RC[255];
  if(tid < 255){
    float Dv = D[tid], Rv = RC[tid];
    float i_f = (float)(tid+1), j_f = 256.f - i_f;
    dist[tid] = Dv/(i_f*i_f) + (tot - 2.f*Rv + Dv)/(j_f*j_f) - 2.f*(Rv - Dv)/(i_f*j_f);
  }
  __syncthreads();
  if(tid == 0){
    float best = dist[0]; int bi = 0;
    for(int i=1;i<255;i++) if(dist[i] > best){ best = dist[i]; bi = i; }
    cutsh = bi + 1; cuts[b] = cutsh;
  }
  __syncthreads();
  int cut = cutsh;
  int k = tid & 127, half = tid >> 7;
  float s = 0.f;
  for(int t=half; t<cut; t+=2) s += hseq[((size_t)b*256+t)*128 + k];
  __shared__ float partial[2][128];
  partial[half][k] = s;
  __syncthreads();
  if(tid < 128){
    corr[b*128+tid] = (partial[0][tid] + partial[1][tid]) / (float)cut;
    last[b*128+tid] = hseq[((size_t)b*256+255)*128 + tid];
  }
}

// ---------------- KAN features ----------------
__global__ __launch_bounds__(256) void feat_kernel(const float* xin, float* feat, int n)
{
  int idx = blockIdx.x*256 + threadIdx.x;
  if(idx >= n) return;
  float xv = xin[idx];
  float* fp = feat + (size_t)idx*7;
  fp[0]=xv;
  fp[1]=sinf(xv); fp[2]=sinf(2.f*xv); fp[3]=sinf(4.f*xv);
  fp[4]=cosf(xv); fp[5]=cosf(2.f*xv); fp[6]=cosf(4.f*xv);
}

// ---------------- generic KAN ----------------
__global__ __launch_bounds__(256) void kan_kernel(
    const float* feat, const float* W1, const float* W2, const float* B1, const float* B2,
    int din, int dout, float* outp)
{
  int j = blockIdx.x, tid = threadIdx.x;
  int h = tid & 31, isub = tid >> 5;
  float acc[32];
  #pragma unroll
  for(int b=0;b<32;b++) acc[b]=0.f;
  float accB2 = 0.f;
  for(int i=isub; i<din; i+=8){
    size_t base = ((size_t)(i*dout + j))*32 + h;
    const float* w1p = W1 + base*7;
    float w1v[7];
    #pragma unroll
    for(int f=0;f<7;f++) w1v[f] = w1p[f];
    float b1v = B1[base];
    float w2v = W2[base];
    if(h == 0) accB2 += B2[i*dout + j];
    const float* fp0 = feat + (size_t)i*7;
    #pragma unroll 4
    for(int b=0;b<32;b++){
      const float* fp = fp0 + (size_t)b*din*7;
      float hv = b1v;
      #pragma unroll
      for(int f=0;f<7;f++) hv = fmaf(fp[f], w1v[f], hv);
      float sv = hv / (1.f + __expf(-hv));   // silu
      acc[b] = fmaf(sv, w2v, acc[b]);
    }
  }
  #pragma unroll
  for(int m=1;m<64;m<<=1){
    #pragma unroll
    for(int b=0;b<32;b++) acc[b] += __shfl_xor(acc[b], m, 64);
    accB2 += __shfl_xor(accB2, m, 64);
  }
  __shared__ float part[4][32];
  __shared__ float partB2[4];
  int lane = tid & 63, wv = tid >> 6;
  if(lane == 0){
    #pragma unroll
    for(int b=0;b<32;b++) part[wv][b] = acc[b];
    partB2[wv] = accB2;
  }
  __syncthreads();
  if(tid < 32){
    int b = tid;
    float r = part[0][b]+part[1][b]+part[2][b]+part[3][b]
            + partB2[0]+partB2[1]+partB2[2]+partB2[3];
    outp[b*dout + j] = r;
  }
}

// ---------------- z / x_z, x1 / x_all mixers ----------------
__global__ __launch_bounds__(256) void zmix_kernel(
    const float* muo, const float* stdo, const float* eps1, const float* last, float* xz)
{
  int idx = blockIdx.x*256 + threadIdx.x;
  if(idx >= 4096) return;
  int b = idx >> 7, k = idx & 127;
  float z = muo[idx] + softplusf(stdo[idx] - 5.f)*eps1[idx];
  xz[b*256 + k]       = last[idx];
  xz[b*256 + 128 + k] = z;
}

__global__ __launch_bounds__(256) void xall_kernel(
    const float* muco, const float* stdco, const float* eps2, const float* x2f, float* xa)
{
  int idx = blockIdx.x*256 + threadIdx.x;
  if(idx >= 4096) return;
  int b = idx >> 7, k = idx & 127;
  xa[b*256 + k]       = muco[idx] + softplusf(stdco[idx] - 5.f)*eps2[idx];
  xa[b*256 + 128 + k] = x2f[idx];
}

// ---------------- causal conv1d + folded BN + GELU (templated, LDS-staged weights) ----------------
template<int CIN, int K>
__global__ __launch_bounds__(256) void conv_t_kernel(
    const float* __restrict__ xin, const float* __restrict__ w,
    const float* __restrict__ epi_s, const float* __restrict__ epi_b,
    float* __restrict__ out, int Cout)
{
  __shared__ float xsh[CIN*32];
  __shared__ float wsh[8*CIN*K];
  int b = blockIdx.x, oc0 = blockIdx.y*8;
  int tid = threadIdx.x;
  {
    const float4* xsrc = (const float4*)(xin + (size_t)b*CIN*32);
    #pragma unroll 2
    for(int i=tid; i<CIN*8; i+=256) ((float4*)xsh)[i] = xsrc[i];
    const float4* wsrc = (const float4*)(w + (size_t)oc0*CIN*K);
    #pragma unroll 4
    for(int i=tid; i<(8*CIN*K)/4; i+=256) ((float4*)wsh)[i] = wsrc[i];
  }
  __syncthreads();
  int l = tid & 31, og = tid >> 5;
  const float* wr = wsh + og*CIN*K;
  float acc = 0.f;
  #pragma unroll 4
  for(int c=0;c<CIN;c++){
    const float* xr = xsh + c*32 + l - (K-1);
    const float* wc = wr + c*K;
    #pragma unroll
    for(int k=0;k<K;k++){
      if(l - (K-1) + k >= 0) acc = fmaf(xr[k], wc[k], acc);
    }
  }
  int o = oc0 + og;
  out[((size_t)b*Cout + o)*32 + l] = geluf(epi_s[o]*acc + epi_b[o]);
}

// ---------------- squeeze-excite (in place) ----------------
__global__ __launch_bounds__(256) void se_kernel(
    float* xio, const float* w1, const float* w2, int C, int R)
{
  __shared__ float mean[256];
  __shared__ float y1[16];
  int b = blockIdx.x, tid = threadIdx.x;
  float* xb = xio + (size_t)b*C*32;
  if(tid < C){
    float s=0.f;
    for(int l=0;l<32;l++) s += xb[tid*32+l];
    mean[tid] = s*(1.f/32.f);
  }
  __syncthreads();
  if(tid < R){
    float s=0.f;
    for(int c=0;c<C;c++) s = fmaf(mean[c], w1[tid*C+c], s);
    y1[tid] = fmaxf(s, 0.f);
  }
  __syncthreads();
  if(tid < C){
    float s=0.f;
    for(int jj=0;jj<R;jj++) s = fmaf(y1[jj], w2[tid*R+jj], s);
    float sc = sigmf(s);
    for(int l=0;l<32;l++) xb[tid*32+l] *= sc;
  }
}

// ---------------- mean over l ----------------
__global__ __launch_bounds__(128) void mean_kernel(const float* xin, float* out)
{
  int b = blockIdx.x, c = threadIdx.x;
  float s = 0.f;
  for(int l=0;l<32;l++) s += xin[((size_t)b*128 + c)*32 + l];
  out[b*128 + c] = s*(1.f/32.f);
}

// ---------------- launch ----------------
extern "C" void kernel_launch(void* const* d_in, const int* in_sizes, int n_in,
                              void* d_out, int out_size, void* d_ws, size_t ws_size,
                              hipStream_t stream)
{
  const float* x    = (const float*)d_in[0];
  const float* we1  = (const float*)d_in[1];
  const float* be1  = (const float*)d_in[2];
  const float* e1g  = (const float*)d_in[3];
  const float* e1b  = (const float*)d_in[4];
  const float* e1m  = (const float*)d_in[5];
  const float* e1v  = (const float*)d_in[6];
  const float* we2  = (const float*)d_in[7];
  const float* be2  = (const float*)d_in[8];
  const float* e2g  = (const float*)d_in[9];
  const float* e2b  = (const float*)d_in[10];
  const float* e2m  = (const float*)d_in[11];
  const float* e2v  = (const float*)d_in[12];
  const float* wih  = (const float*)d_in[13];
  const float* whh  = (const float*)d_in[14];
  const float* bih  = (const float*)d_in[15];
  const float* bhh  = (const float*)d_in[16];
  const float* muW1 = (const float*)d_in[17];
  const float* muW2 = (const float*)d_in[18];
  const float* muB1 = (const float*)d_in[19];
  const float* muB2 = (const float*)d_in[20];
  const float* sdW1 = (const float*)d_in[21];
  const float* sdW2 = (const float*)d_in[22];
  const float* sdB1 = (const float*)d_in[23];
  const float* sdB2 = (const float*)d_in[24];
  const float* mcW1 = (const float*)d_in[25];
  const float* mcW2 = (const float*)d_in[26];
  const float* mcB1 = (const float*)d_in[27];
  const float* mcB2 = (const float*)d_in[28];
  const float* scW1 = (const float*)d_in[29];
  const float* scW2 = (const float*)d_in[30];
  const float* scB1 = (const float*)d_in[31];
  const float* scB2 = (const float*)d_in[32];
  const float* fcW1 = (const float*)d_in[33];
  const float* fcW2 = (const float*)d_in[34];
  const float* fcB1 = (const float*)d_in[35];
  const float* fcB2 = (const float*)d_in[36];
  const float* wc1  = (const float*)d_in[37];
  const float* bc1  = (const float*)d_in[38];
  const float* c1g  = (const float*)d_in[39];
  const float* c1b  = (const float*)d_in[40];
  const float* c1m  = (const float*)d_in[41];
  const float* c1v  = (const float*)d_in[42];
  const float* se1w1= (const float*)d_in[43];
  const float* se1w2= (const float*)d_in[44];
  const float* wc2  = (const float*)d_in[45];
  const float* bc2  = (const float*)d_in[46];
  const float* c2g  = (const float*)d_in[47];
  const float* c2b  = (const float*)d_in[48];
  const float* c2m  = (const float*)d_in[49];
  const float* c2v  = (const float*)d_in[50];
  const float* se2w1= (const float*)d_in[51];
  const float* se2w2= (const float*)d_in[52];
  const float* wc3  = (const float*)d_in[53];
  const float* bc3  = (const float*)d_in[54];
  const float* c3g  = (const float*)d_in[55];
  const float* c3b  = (const float*)d_in[56];
  const float* c3m  = (const float*)d_in[57];
  const float* c3v  = (const float*)d_in[58];
  const float* eps1 = (const float*)d_in[59];
  const float* eps2 = (const float*)d_in[60];

  float* ws = (float*)d_ws;

  prep_kernel<<<2446, 256, 0, stream>>>(we1, be1, e1g,e1b,e1m,e1v,
      we2, be2,e2g,e2b,e2m,e2v, wih,whh,bih,bhh,
      bc1,c1g,c1b,c1m,c1v, bc2,c2g,c2b,c2m,c2v, bc3,c3g,c3b,c3m,c3v, ws);

  encoder_kernel<<<256, 256, 0, stream>>>(x, ws+OFF_W1F, ws+OFF_B1F,
      ws+OFF_S2E, ws+OFF_B2E, (const bf16*)(ws+OFF_WE2B), ws+OFF_XSRC);

  gates_kernel<<<256, 256, 0, stream>>>(ws+OFF_XSRC, ws+OFF_WIHT, ws+OFF_BIASG, ws+OFF_GX);
  lstm_kernel<<<32, 512, 0, stream>>>(ws+OFF_GX, ws+OFF_WHHT, ws+OFF_HSEQ);

  hn_kernel<<<8192, 64, 0, stream>>>(ws+OFF_HSEQ, ws+OFF_HN);
  pc_kernel<<<256, 256, 0, stream>>>(ws+OFF_HN, ws+OFF_PCOL, ws+OFF_CCOL);
  cutcorr_kernel<<<32, 256, 0, stream>>>(ws+OFF_PCOL, ws+OFF_CCOL, ws+OFF_HSEQ,
      ws+OFF_LAST, ws+OFF_CORR, (int*)(ws+OFF_CUTS));

  feat_kernel<<<16, 256, 0, stream>>>(ws+OFF_CORR, ws+OFF_FEATA, 4096);
  kan_kernel<<<128, 256, 0, stream>>>(ws+OFF_FEATA, muW1, muW2, muB1, muB2, 128, 128, ws+OFF_MUO);
  kan_kernel<<<128, 256, 0, stream>>>(ws+OFF_FEATA, sdW1, sdW2, sdB1, sdB2, 128, 128, ws+OFF_STDO);
  zmix_kernel<<<16, 256, 0, stream>>>(ws+OFF_MUO, ws+OFF_STDO, eps1, ws+OFF_LAST, ws+OFF_XZ);
  feat_kernel<<<32, 256, 0, stream>>>(ws+OFF_XZ, ws+OFF_FEATB, 8192);
  kan_kernel<<<128, 256, 0, stream>>>(ws+OFF_FEATB, mcW1, mcW2, mcB1, mcB2, 256, 128, ws+OFF_MUCO);
  kan_kernel<<<128, 256, 0, stream>>>(ws+OFF_FEATB, scW1, scW2, scB1, scB2, 256, 128, ws+OFF_STDCO);

  conv_t_kernel<256,8><<<dim3(32,16), 256, 0, stream>>>(x, wc1, ws+OFF_EPI1S, ws+OFF_EPI1B, ws+OFF_XC1, 128);
  se_kernel<<<32, 256, 0, stream>>>(ws+OFF_XC1, se1w1, se1w2, 128, 8);
  conv_t_kernel<128,5><<<dim3(32,32), 256, 0, stream>>>(ws+OFF_XC1, wc2, ws+OFF_EPI2S, ws+OFF_EPI2B, ws+OFF_XC2, 256);
  se_kernel<<<32, 256, 0, stream>>>(ws+OFF_XC2, se2w1, se2w2, 256, 16);
  conv_t_kernel<256,3><<<dim3(32,16), 256, 0, stream>>>(ws+OFF_XC2, wc3, ws+OFF_EPI3S, ws+OFF_EPI3B, ws+OFF_XC3, 128);
  mean_kernel<<<32, 128, 0, stream>>>(ws+OFF_XC3, ws+OFF_X2F);

  xall_kernel<<<16, 256, 0, stream>>>(ws+OFF_MUCO, ws+OFF_STDCO, eps2, ws+OFF_X2F, ws+OFF_XALL);
  feat_kernel<<<32, 256, 0, stream>>>(ws+OFF_XALL, ws+OFF_FEATC, 8192);
  kan_kernel<<<10, 256, 0, stream>>>(ws+OFF_FEATC, fcW1, fcW2, fcB1, fcB2, 256, 10, (float*)d_out);
}

// Round 5
// 2153.138 us; speedup vs baseline: 1.8252x; 1.0716x over previous
//
#include <hip/hip_runtime.h>
#include <hip/hip_bf16.h>
#include <math.h>

typedef __hip_bfloat16 bf16;

#define DEV static __device__ __forceinline__

DEV float geluf(float x){ return 0.5f*x*(1.0f + erff(x*0.70710678118654752f)); }
DEV float sigmf(float x){ return 1.0f/(1.0f + __expf(-x)); }
DEV float softplusf(float x){ return (x > 15.f) ? x : log1pf(__expf(x)); }
DEV float tanhfast(float x){ float e = __expf(2.f*x); return fmaf(-2.f, 1.f/(e+1.f), 1.f); }

typedef __attribute__((ext_vector_type(8))) short v8s;   // 8 bf16 (4 VGPRs)
typedef __attribute__((ext_vector_type(4))) float v4f;   // 4 fp32 acc
typedef _Float16 f16;
typedef f16 h2 __attribute__((ext_vector_type(2)));

DEV float dot2f(h2 a, h2 b, float c){
#if __has_builtin(__builtin_amdgcn_fdot2)
  return __builtin_amdgcn_fdot2(a, b, c, false);
#else
  return fmaf((float)a.y, (float)b.y, fmaf((float)a.x, (float)b.x, c));
#endif
}

// ---------------- workspace layout (float offsets) ----------------
enum : size_t {
  OFF_W1F   = 0,        // 2048  folded enc conv1 weights (256x8)
  OFF_B1F   = 2048,     // 256
  OFF_S2E   = 2304,     // 64
  OFF_B2E   = 2368,     // 64
  OFF_WIHT  = 2432,     // 32768 w_ih^T (64x512)
  OFF_BIASG = 35200,    // 512   b_ih+b_hh
  OFF_WHHT  = 35712,    // whh packed f16 pairs: h2[64][512] (32768 slots)
  OFF_EPI1S = 101248,   // 128
  OFF_EPI1B = 101376,   // 128
  OFF_EPI2S = 101504,   // 256
  OFF_EPI2B = 101760,   // 256
  OFF_EPI3S = 102016,   // 128
  OFF_EPI3B = 102144,   // 128
  OFF_WE2B  = 102272,   // 262144 floats = 524288 bf16: we2 repacked [o][e][f]
  OFF_XSRC  = 364416,   // 524288 (B,T,64)
  OFF_GX    = 888704,   // 4194304 (B,T,512); reused as conv partial buffer after lstm
  OFF_HSEQ  = 5083008,  // 1048576 (B,T,128)
  OFF_HN    = 6131584,  // 1048576
  OFF_PCOL  = 7180160,  // 8192
  OFF_CCOL  = 7188352,  // 8192
  OFF_CUTS  = 7196544,  // 32 (int)
  OFF_LAST  = 7196576,  // 4096
  OFF_CORR  = 7200672,  // 4096
  OFF_FEATA = 7204768,  // 28672 (B,128,7)
  OFF_MUO   = 7233440,  // 4096
  OFF_STDO  = 7237536,  // 4096
  OFF_XZ    = 7241632,  // 8192 (B,256)
  OFF_FEATB = 7249824,  // 57344 (B,256,7)
  OFF_MUCO  = 7307168,  // 4096
  OFF_STDCO = 7311264,  // 4096
  OFF_XC1   = 7315360,  // 131072 (B,128,32)
  OFF_XC2   = 7446432,  // 262144 (B,256,32)
  OFF_XC3   = 7708576,  // 131072 (unused now)
  OFF_X2F   = 7839648,  // 4096
  OFF_XALL  = 7843744,  // 8192
  OFF_FEATC = 7851936,  // 57344
  WS_FLOATS = 7909280   // ~31.6 MB
};

// ---------------- prep: fold BN, transpose/pack LSTM weights, repack we2 ----------------
__global__ __launch_bounds__(256) void prep_kernel(
    const float* we1, const float* be1,
    const float* e1g, const float* e1b, const float* e1m, const float* e1v,
    const float* we2, const float* be2, const float* e2g, const float* e2b, const float* e2m, const float* e2v,
    const float* wih, const float* whh, const float* bih, const float* bhh,
    const float* bc1, const float* c1g, const float* c1b, const float* c1m, const float* c1v,
    const float* bc2, const float* c2g, const float* c2b, const float* c2m, const float* c2v,
    const float* bc3, const float* c3g, const float* c3b, const float* c3m, const float* c3v,
    float* ws)
{
  int idx = blockIdx.x*256 + threadIdx.x;
  if(idx < 2048){
    int o = idx>>3;
    float s = e1g[o] * rsqrtf(e1v[o] + 1e-5f);
    ws[OFF_W1F + idx] = we1[idx] * s;
  } else if(idx < 2304){
    int o = idx - 2048;
    float s = e1g[o] * rsqrtf(e1v[o] + 1e-5f);
    ws[OFF_B1F + o] = s*(be1[o] - e1m[o]) + e1b[o];
  } else if(idx < 2368){
    int e = idx - 2304;
    float s = e2g[e] * rsqrtf(e2v[e] + 1e-5f);
    ws[OFF_S2E + e] = s;
    ws[OFF_B2E + e] = s*(be2[e] - e2m[e]) + e2b[e];
  } else if(idx < 35136){
    int q = idx - 2368; int e = q>>9, g = q&511;
    ws[OFF_WIHT + q] = wih[g*64 + e];
  } else if(idx < 35648){
    int g = idx - 35136;
    ws[OFF_BIASG + g] = bih[g] + bhh[g];
  } else if(idx < 101184){
    int q = idx - 35648;
    if(q < 32768){
      int k2 = q>>9, g = q&511;
      h2 v;
      v.x = (f16)whh[g*128 + 2*k2];
      v.y = (f16)whh[g*128 + 2*k2 + 1];
      ((h2*)(ws + OFF_WHHT))[q] = v;
    }
  } else if(idx < 101312){
    int o = idx - 101184;
    float s = c1g[o] * rsqrtf(c1v[o] + 1e-3f);
    ws[OFF_EPI1S + o] = s;
    ws[OFF_EPI1B + o] = s*(bc1[o] - c1m[o]) + c1b[o];
  } else if(idx < 101568){
    int o = idx - 101312;
    float s = c2g[o] * rsqrtf(c2v[o] + 1e-3f);
    ws[OFF_EPI2S + o] = s;
    ws[OFF_EPI2B + o] = s*(bc2[o] - c2m[o]) + c2b[o];
  } else if(idx < 101696){
    int o = idx - 101568;
    float s = c3g[o] * rsqrtf(c3v[o] + 1e-3f);
    ws[OFF_EPI3S + o] = s;
    ws[OFF_EPI3B + o] = s*(bc3[o] - c3m[o]) + c3b[o];
  } else if(idx < 625984){
    // we2 repack: [e][o*32+f] f32 -> [o][e][f] bf16
    int q = idx - 101696;
    int o = q >> 11, rem = q & 2047;
    int e = rem >> 5, f = rem & 31;
    bf16* Wr = (bf16*)(ws + OFF_WE2B);
    Wr[q] = __float2bfloat16(we2[(size_t)e*8192 + o*32 + f]);
  }
}

// ---------------- encoder: conv1(1x8 SAME)+BN+GELU fused into bf16 MFMA GEMM ----------------
// grid 256 = (b 32) x (tg 8); M-tile = 32 t, N = 64 e, K = 64 chunks x (4o x 32f = 128)
__global__ __launch_bounds__(256,1) void encoder_kernel(
    const float* __restrict__ x, const float* __restrict__ w1f, const float* __restrict__ b1f,
    const float* __restrict__ s2e, const float* __restrict__ b2e,
    const bf16* __restrict__ Wr, float* __restrict__ x_src)
{
  __shared__ float xs[39*32];
  __shared__ float w1s[2048];
  __shared__ float b1s[256];
  __shared__ __align__(16) unsigned short At[2][32*136];   // [t][k], stride 136 (pad)
  __shared__ __align__(16) unsigned short Bt[2][4*2560];   // 4 sub-tiles [e][f], stride 40 (pad)

  int blk = blockIdx.x; int b = blk>>3; int t0 = (blk&7)*32;
  int tid = threadIdx.x;

  for(int i=tid;i<2048;i+=256) w1s[i] = w1f[i];
  b1s[tid] = b1f[tid];
  for(int i=tid;i<39*32;i+=256){
    int r=i>>5, f=i&31; int t=t0-3+r;
    xs[i] = (t>=0 && t<256) ? x[(b*256+t)*32+f] : 0.f;
  }
  __syncthreads();

  int f = tid & 31, tq = tid >> 5;
  int lane = tid & 63, w = tid >> 6;
  int wm = w & 1, wn = w >> 1;
  int m0 = wm*16, n0 = wn*32;
  int l15 = lane & 15, quad = lane >> 4;

  const v8s* Wv = (const v8s*)Wr;

  auto stage = [&](int cc, int buf){
    // B prefetch loads first (latency covered by A compute)
    v8s bw[4];
    #pragma unroll
    for(int i=0;i<4;i++) bw[i] = Wv[cc*1024 + i*256 + tid];
    // A: conv1 + BN + GELU, bf16 (bit-identical math to previous rounds)
    unsigned short aval[16];
    #pragma unroll
    for(int ol=0;ol<4;ol++){
      int o = cc*4 + ol;
      float wv[8];
      #pragma unroll
      for(int j=0;j<8;j++) wv[j] = w1s[o*8+j];
      float bb = b1s[o];
      #pragma unroll
      for(int i=0;i<4;i++){
        int tl = tq*4 + i;
        float c = bb;
        #pragma unroll
        for(int j=0;j<8;j++) c = fmaf(wv[j], xs[(tl+j)*32+f], c);
        aval[ol*4+i] = ((__hip_bfloat16_raw)__float2bfloat16(geluf(c))).x;
      }
    }
    #pragma unroll
    for(int ol=0;ol<4;ol++){
      #pragma unroll
      for(int i=0;i<4;i++)
        At[buf][(tq*4+i)*136 + ol*32 + f] = aval[ol*4+i];
    }
    #pragma unroll
    for(int i=0;i<4;i++){
      int j = i*256 + tid;
      int ol = j>>8, e = (j&255)>>2, f8 = j&3;
      *(v8s*)&Bt[buf][ol*2560 + e*40 + f8*8] = bw[i];
    }
  };

  stage(0, 0);
  __syncthreads();

  v4f acc0 = {0.f,0.f,0.f,0.f}, acc1 = {0.f,0.f,0.f,0.f};

  for(int c=0;c<64;c++){
    int p = c & 1, q = p ^ 1;
    if(c < 63) stage(c+1, q);
    #pragma unroll
    for(int ol=0;ol<4;ol++){
      v8s av = *(const v8s*)&At[p][(m0+l15)*136 + ol*32 + quad*8];
      v8s b0 = *(const v8s*)&Bt[p][ol*2560 + (n0+l15)*40 + quad*8];
      v8s b1 = *(const v8s*)&Bt[p][ol*2560 + (n0+16+l15)*40 + quad*8];
      acc0 = __builtin_amdgcn_mfma_f32_16x16x32_bf16(av, b0, acc0, 0, 0, 0);
      acc1 = __builtin_amdgcn_mfma_f32_16x16x32_bf16(av, b1, acc1, 0, 0, 0);
    }
    __syncthreads();
  }

  // epilogue: D row = quad*4+reg (m), col = l15 (n)
  #pragma unroll
  for(int r=0;r<4;r++){
    int t = t0 + m0 + quad*4 + r;
    int e0 = n0 + l15;
    float v0 = geluf(s2e[e0]*acc0[r] + b2e[e0]);
    x_src[((size_t)(b*256+t))*64 + e0] = v0;
    int e1 = e0 + 16;
    float v1 = geluf(s2e[e1]*acc1[r] + b2e[e1]);
    x_src[((size_t)(b*256+t))*64 + e1] = v1;
  }
}

// ---------------- gates_x = x_src @ w_ih^T + bias ----------------
__global__ __launch_bounds__(256) void gates_kernel(
    const float* x_src, const float* wihT, const float* biasg, float* gx)
{
  __shared__ float xsh[32*64];
  int blk = blockIdx.x; int b = blk>>3, t0 = (blk&7)*32;
  int tid = threadIdx.x;
  for(int i=tid;i<2048;i+=256) xsh[i] = x_src[((size_t)b*256+t0)*64 + i];
  __syncthreads();
  int g0 = tid, g1 = tid + 256;
  float acc0[32], acc1[32];
  #pragma unroll
  for(int tt=0;tt<32;tt++){ acc0[tt]=0.f; acc1[tt]=0.f; }
  for(int e=0;e<64;e++){
    float w0 = wihT[e*512+g0], w1 = wihT[e*512+g1];
    #pragma unroll
    for(int tt=0;tt<32;tt++){
      float xv = xsh[tt*64+e];
      acc0[tt] = fmaf(xv, w0, acc0[tt]);
      acc1[tt] = fmaf(xv, w1, acc1[tt]);
    }
  }
  float bg0 = biasg[g0], bg1 = biasg[g1];
  #pragma unroll
  for(int tt=0;tt<32;tt++){
    gx[((size_t)b*256+t0+tt)*512 + g0] = acc0[tt] + bg0;
    gx[((size_t)b*256+t0+tt)*512 + g1] = acc1[tt] + bg1;
  }
}

// ---------------- LSTM: 32 blocks x 128 threads, thread owns unit n (i,f,g,o) ----------------
// w_hh in 256 VGPRs as f16 pairs; h in f16 double-buffered LDS; one barrier/step
__global__ __launch_bounds__(128,1) void lstm_kernel(
    const float* __restrict__ gates_x, const float* __restrict__ whh16f, float* __restrict__ hseq)
{
  __shared__ __align__(16) f16 hsh[2][128];
  int b = blockIdx.x, n = threadIdx.x;
  const h2* W = (const h2*)whh16f;
  h2 wi[64], wf[64], wg[64], wo[64];
  #pragma unroll
  for(int k=0;k<64;k++){
    wi[k] = W[k*512 + n];
    wf[k] = W[k*512 + 128 + n];
    wg[k] = W[k*512 + 256 + n];
    wo[k] = W[k*512 + 384 + n];
  }
  hsh[0][n] = (f16)0.f;
  float c = 0.f;
  const float* gx = gates_x + (size_t)b*256*512 + n;
  float nai = gx[0], naf = gx[128], nag = gx[256], nao = gx[384];
  __syncthreads();
  int p = 0;
  for(int tb=0;tb<64;tb++){
    float hq[4];
    #pragma unroll
    for(int j=0;j<4;j++){
      int t = tb*4 + j;
      float ai = nai, af = naf, ag = nag, ao = nao;
      if(t < 255){
        const float* gp = gx + (size_t)(t+1)*512;
        nai = gp[0]; naf = gp[128]; nag = gp[256]; nao = gp[384];
      }
      const uint4* hv4 = (const uint4*)&hsh[p][0];
      #pragma unroll
      for(int kk=0;kk<16;kk++){
        uint4 hv = hv4[kk];
        h2 q0 = __builtin_bit_cast(h2, hv.x);
        h2 q1 = __builtin_bit_cast(h2, hv.y);
        h2 q2 = __builtin_bit_cast(h2, hv.z);
        h2 q3 = __builtin_bit_cast(h2, hv.w);
        ai = dot2f(q0, wi[kk*4+0], ai); af = dot2f(q0, wf[kk*4+0], af);
        ag = dot2f(q0, wg[kk*4+0], ag); ao = dot2f(q0, wo[kk*4+0], ao);
        ai = dot2f(q1, wi[kk*4+1], ai); af = dot2f(q1, wf[kk*4+1], af);
        ag = dot2f(q1, wg[kk*4+1], ag); ao = dot2f(q1, wo[kk*4+1], ao);
        ai = dot2f(q2, wi[kk*4+2], ai); af = dot2f(q2, wf[kk*4+2], af);
        ag = dot2f(q2, wg[kk*4+2], ag); ao = dot2f(q2, wo[kk*4+2], ao);
        ai = dot2f(q3, wi[kk*4+3], ai); af = dot2f(q3, wf[kk*4+3], af);
        ag = dot2f(q3, wg[kk*4+3], ag); ao = dot2f(q3, wo[kk*4+3], ao);
      }
      float iv = sigmf(ai), fv = sigmf(af);
      float gv = tanhfast(ag), ov = sigmf(ao);
      c = fv*c + iv*gv;
      float h = ov*tanhfast(c);
      hsh[p^1][n] = (f16)h;
      hq[j] = h;
      __syncthreads();
      p ^= 1;
    }
    float* hp = hseq + ((size_t)b*256 + tb*4)*128 + n;
    hp[0]=hq[0]; hp[128]=hq[1]; hp[256]=hq[2]; hp[384]=hq[3];
  }
}

// ---------------- row-normalize hidden ----------------
__global__ __launch_bounds__(64) void hn_kernel(const float* hseq, float* hn)
{
  size_t row = blockIdx.x; int lane = threadIdx.x;
  const float* hp = hseq + row*128;
  float v0 = hp[lane], v1 = hp[lane+64];
  float ss = v0*v0 + v1*v1;
  #pragma unroll
  for(int m=1;m<64;m<<=1) ss += __shfl_xor(ss, m, 64);
  float r = 1.f / fmaxf(sqrtf(ss), 1e-8f);
  hn[row*128 + lane]      = v0*r;
  hn[row*128 + 64 + lane] = v1*r;
}

// ---------------- cluster: per-column partial/full sums of symmetric sim ----------------
__global__ __launch_bounds__(256) void pc_kernel(const float* hn, float* pcol, float* ccol)
{
  int blk = blockIdx.x; int b = blk>>3, chunk = blk&7;
  int tid = threadIdx.x; int il = tid & 31, ts = tid >> 5;
  int i = chunk*32 + il;
  const float4* hb = (const float4*)(hn + (size_t)b*32768);
  float4 hi[32];
  #pragma unroll
  for(int r=0;r<32;r++) hi[r] = hb[(size_t)i*32 + r];
  float ps=0.f, cs=0.f;
  for(int t=ts*32; t<ts*32+32; t++){
    float dx=0.f, dy=0.f, dz=0.f, dw=0.f;
    #pragma unroll
    for(int r=0;r<32;r++){
      float4 hv = hb[(size_t)t*32 + r];
      dx = fmaf(hi[r].x, hv.x, dx);
      dy = fmaf(hi[r].y, hv.y, dy);
      dz = fmaf(hi[r].z, hv.z, dz);
      dw = fmaf(hi[r].w, hv.w, dw);
    }
    float dot = (dx+dy)+(dz+dw);
    float sim = (t==i) ? 0.f : expf(-5.5f*(1.0f - dot));
    cs += sim;
    if(t < i) ps += sim;
  }
  __shared__ float red[16][32];
  red[ts][il] = ps; red[8+ts][il] = cs;
  __syncthreads();
  if(tid < 32){
    float s=0.f;
    for(int r=0;r<8;r++) s += red[r][tid];
    pcol[b*256 + chunk*32 + tid] = s;
  } else if(tid < 64){
    int c2 = tid - 32; float s=0.f;
    for(int r=0;r<8;r++) s += red[8+r][c2];
    ccol[b*256 + chunk*32 + c2] = s;
  }
}

// ---------------- prefix + dist + argmax + corr/last ----------------
__global__ __launch_bounds__(256) void cutcorr_kernel(
    const float* pcol, const float* ccol, const float* hseq,
    float* last, float* corr, int* cuts)
{
  int b = blockIdx.x, tid = threadIdx.x;
  __shared__ float D[256], RC[256], dist[256];
  __shared__ int cutsh;
  if(tid == 0){
    float d=0.f, r=0.f;
    for(int i=0;i<256;i++){
      d += 2.f*pcol[b*256+i]; D[i]=d;
      r += ccol[b*256+i];     RC[i]=r;
    }
  }
  __syncthreads();
  float tot = RC[255];
  if(tid < 255){
    float Dv = D[tid], Rv = RC[tid];
    float i_f = (float)(tid+1), j_f = 256.f - i_f;
    dist[tid] = Dv/(i_f*i_f) + (tot - 2.f*Rv + Dv)/(j_f*j_f) - 2.f*(Rv - Dv)/(i_f*j_f);
  }
  __syncthreads();
  if(tid == 0){
    float best = dist[0]; int bi = 0;
    for(int i=1;i<255;i++) if(dist[i] > best){ best = dist[i]; bi = i; }
    cutsh = bi + 1; cuts[b] = cutsh;
  }
  __syncthreads();
  int cut = cutsh;
  int k = tid & 127, half = tid >> 7;
  float s = 0.f;
  for(int t=half; t<cut; t+=2) s += hseq[((size_t)b*256+t)*128 + k];
  __shared__ float partial[2][128];
  partial[half][k] = s;
  __syncthreads();
  if(tid < 128){
    corr[b*128+tid] = (partial[0][tid] + partial[1][tid]) / (float)cut;
    last[b*128+tid] = hseq[((size_t)b*256+255)*128 + tid];
  }
}

// ---------------- KAN features ----------------
__global__ __launch_bounds__(256) void feat_kernel(const float* xin, float* feat, int n)
{
  int idx = blockIdx.x*256 + threadIdx.x;
  if(idx >= n) return;
  float xv = xin[idx];
  float* fp = feat + (size_t)idx*7;
  fp[0]=xv;
  fp[1]=sinf(xv); fp[2]=sinf(2.f*xv); fp[3]=sinf(4.f*xv);
  fp[4]=cosf(xv); fp[5]=cosf(2.f*xv); fp[6]=cosf(4.f*xv);
}

// ---------------- generic KAN ----------------
__global__ __launch_bounds__(256) void kan_kernel(
    const float* feat, const float* W1, const float* W2, const float* B1, const float* B2,
    int din, int dout, float* outp)
{
  int j = blockIdx.x, tid = threadIdx.x;
  int h = tid & 31, isub = tid >> 5;
  float acc[32];
  #pragma unroll
  for(int b=0;b<32;b++) acc[b]=0.f;
  float accB2 = 0.f;
  for(int i=isub; i<din; i+=8){
    size_t base = ((size_t)(i*dout + j))*32 + h;
    const float* w1p = W1 + base*7;
    float w1v[7];
    #pragma unroll
    for(int f=0;f<7;f++) w1v[f] = w1p[f];
    float b1v = B1[base];
    float w2v = W2[base];
    if(h == 0) accB2 += B2[i*dout + j];
    const float* fp0 = feat + (size_t)i*7;
    #pragma unroll 4
    for(int b=0;b<32;b++){
      const float* fp = fp0 + (size_t)b*din*7;
      float hv = b1v;
      #pragma unroll
      for(int f=0;f<7;f++) hv = fmaf(fp[f], w1v[f], hv);
      float sv = hv / (1.f + __expf(-hv));   // silu
      acc[b] = fmaf(sv, w2v, acc[b]);
    }
  }
  #pragma unroll
  for(int m=1;m<64;m<<=1){
    #pragma unroll
    for(int b=0;b<32;b++) acc[b] += __shfl_xor(acc[b], m, 64);
    accB2 += __shfl_xor(accB2, m, 64);
  }
  __shared__ float part[4][32];
  __shared__ float partB2[4];
  int lane = tid & 63, wv = tid >> 6;
  if(lane == 0){
    #pragma unroll
    for(int b=0;b<32;b++) part[wv][b] = acc[b];
    partB2[wv] = accB2;
  }
  __syncthreads();
  if(tid < 32){
    int b = tid;
    float r = part[0][b]+part[1][b]+part[2][b]+part[3][b]
            + partB2[0]+partB2[1]+partB2[2]+partB2[3];
    outp[b*dout + j] = r;
  }
}

// ---------------- z / x_z, x1 / x_all mixers ----------------
__global__ __launch_bounds__(256) void zmix_kernel(
    const float* muo, const float* stdo, const float* eps1, const float* last, float* xz)
{
  int idx = blockIdx.x*256 + threadIdx.x;
  if(idx >= 4096) return;
  int b = idx >> 7, k = idx & 127;
  float z = muo[idx] + softplusf(stdo[idx] - 5.f)*eps1[idx];
  xz[b*256 + k]       = last[idx];
  xz[b*256 + 128 + k] = z;
}

__global__ __launch_bounds__(256) void xall_kernel(
    const float* muco, const float* stdco, const float* eps2, const float* x2f, float* xa)
{
  int idx = blockIdx.x*256 + threadIdx.x;
  if(idx >= 4096) return;
  int b = idx >> 7, k = idx & 127;
  xa[b*256 + k]       = muco[idx] + softplusf(stdco[idx] - 5.f)*eps2[idx];
  xa[b*256 + 128 + k] = x2f[idx];
}

// ---------------- causal conv1d partial sums (c-chunked, VALU-bound) ----------------
// grid (b=32, NCH c-chunks); block COUT*LG threads; thread = (o, l-group of 32/LG)
template<int CIN, int K, int COUT, int NCH, int LG>
__global__ __launch_bounds__(COUT*LG, 1) void convp_kernel(
    const float* __restrict__ xin, const float* __restrict__ w, float* __restrict__ part)
{
  constexpr int L = 32/LG;
  constexpr int CCH = CIN/NCH;
  __shared__ float xsh[CCH*32];
  int b = blockIdx.x, ch = blockIdx.y;
  int tid = threadIdx.x;
  for(int i=tid; i<CCH*32; i+=COUT*LG) xsh[i] = xin[((size_t)b*CIN + ch*CCH)*32 + i];
  __syncthreads();
  int o = tid / LG, lh = tid % LG;
  int l0 = lh*L;
  float acc[L];
  #pragma unroll
  for(int j=0;j<L;j++) acc[j]=0.f;
  const float* wrow = w + ((size_t)o*CIN + ch*CCH)*K;
  for(int c=0;c<CCH;c++){
    float wv[K];
    #pragma unroll
    for(int k=0;k<K;k++) wv[k] = wrow[c*K + k];
    float xr[L+K-1];
    #pragma unroll
    for(int i=0;i<L+K-1;i++){
      int li = l0 - (K-1) + i;
      xr[i] = (li>=0) ? xsh[c*32+li] : 0.f;
    }
    #pragma unroll
    for(int j=0;j<L;j++){
      #pragma unroll
      for(int k=0;k<K;k++) acc[j] = fmaf(xr[j+k], wv[k], acc[j]);
    }
  }
  float* pp = part + (((size_t)ch*32 + b)*COUT + o)*32 + l0;
  #pragma unroll
  for(int j=0;j<L;j++) pp[j] = acc[j];
}

// ---------------- SE fused with partial-reduce + BN + GELU ----------------
template<int C, int R, int NP>
__global__ __launch_bounds__(C,1) void sef_kernel(
    const float* __restrict__ part, const float* __restrict__ epi_s, const float* __restrict__ epi_b,
    const float* __restrict__ w1, const float* __restrict__ w2, float* __restrict__ out)
{
  __shared__ float mean[C];
  __shared__ float y1[R];
  int b = blockIdx.x, c = threadIdx.x;
  float g[32];
  #pragma unroll
  for(int l=0;l<32;l++) g[l]=0.f;
  for(int p=0;p<NP;p++){
    const float* pp = part + (((size_t)p*32 + b)*C + c)*32;
    #pragma unroll
    for(int l=0;l<32;l++) g[l] += pp[l];
  }
  float s = epi_s[c], bb = epi_b[c];
  float m = 0.f;
  #pragma unroll
  for(int l=0;l<32;l++){ g[l] = geluf(s*g[l]+bb); m += g[l]; }
  mean[c] = m*(1.f/32.f);
  __syncthreads();
  if(c < R){
    float t=0.f;
    for(int k=0;k<C;k++) t = fmaf(mean[k], w1[c*C+k], t);
    y1[c] = fmaxf(t,0.f);
  }
  __syncthreads();
  float t=0.f;
  #pragma unroll
  for(int k=0;k<R;k++) t = fmaf(y1[k], w2[c*R+k], t);
  float sc = sigmf(t);
  float* op = out + ((size_t)b*C + c)*32;
  #pragma unroll
  for(int l=0;l<32;l++) op[l] = g[l]*sc;
}

// ---------------- conv3 partial-reduce + BN + GELU + mean over l ----------------
__global__ __launch_bounds__(128,1) void mean3f_kernel(
    const float* __restrict__ part, const float* __restrict__ epi_s, const float* __restrict__ epi_b,
    float* __restrict__ x2f)
{
  int b = blockIdx.x, c = threadIdx.x;
  float g[32];
  #pragma unroll
  for(int l=0;l<32;l++) g[l]=0.f;
  for(int p=0;p<8;p++){
    const float* pp = part + (((size_t)p*32 + b)*128 + c)*32;
    #pragma unroll
    for(int l=0;l<32;l++) g[l] += pp[l];
  }
  float s = epi_s[c], bb = epi_b[c];
  float m = 0.f;
  #pragma unroll
  for(int l=0;l<32;l++) m += geluf(s*g[l]+bb);
  x2f[b*128 + c] = m*(1.f/32.f);
}

// ---------------- launch ----------------
extern "C" void kernel_launch(void* const* d_in, const int* in_sizes, int n_in,
                              void* d_out, int out_size, void* d_ws, size_t ws_size,
                              hipStream_t stream)
{
  const float* x    = (const float*)d_in[0];
  const float* we1  = (const float*)d_in[1];
  const float* be1  = (const float*)d_in[2];
  const float* e1g  = (const float*)d_in[3];
  const float* e1b  = (const float*)d_in[4];
  const float* e1m  = (const float*)d_in[5];
  const float* e1v  = (const float*)d_in[6];
  const float* we2  = (const float*)d_in[7];
  const float* be2  = (const float*)d_in[8];
  const float* e2g  = (const float*)d_in[9];
  const float* e2b  = (const float*)d_in[10];
  const float* e2m  = (const float*)d_in[11];
  const float* e2v  = (const float*)d_in[12];
  const float* wih  = (const float*)d_in[13];
  const float* whh  = (const float*)d_in[14];
  const float* bih  = (const float*)d_in[15];
  const float* bhh  = (const float*)d_in[16];
  const float* muW1 = (const float*)d_in[17];
  const float* muW2 = (const float*)d_in[18];
  const float* muB1 = (const float*)d_in[19];
  const float* muB2 = (const float*)d_in[20];
  const float* sdW1 = (const float*)d_in[21];
  const float* sdW2 = (const float*)d_in[22];
  const float* sdB1 = (const float*)d_in[23];
  const float* sdB2 = (const float*)d_in[24];
  const float* mcW1 = (const float*)d_in[25];
  const float* mcW2 = (const float*)d_in[26];
  const float* mcB1 = (const float*)d_in[27];
  const float* mcB2 = (const float*)d_in[28];
  const float* scW1 = (const float*)d_in[29];
  const float* scW2 = (const float*)d_in[30];
  const float* scB1 = (const float*)d_in[31];
  const float* scB2 = (const float*)d_in[32];
  const float* fcW1 = (const float*)d_in[33];
  const float* fcW2 = (const float*)d_in[34];
  const float* fcB1 = (const float*)d_in[35];
  const float* fcB2 = (const float*)d_in[36];
  const float* wc1  = (const float*)d_in[37];
  const float* bc1  = (const float*)d_in[38];
  const float* c1g  = (const float*)d_in[39];
  const float* c1b  = (const float*)d_in[40];
  const float* c1m  = (const float*)d_in[41];
  const float* c1v  = (const float*)d_in[42];
  const float* se1w1= (const float*)d_in[43];
  const float* se1w2= (const float*)d_in[44];
  const float* wc2  = (const float*)d_in[45];
  const float* bc2  = (const float*)d_in[46];
  const float* c2g  = (const float*)d_in[47];
  const float* c2b  = (const float*)d_in[48];
  const float* c2m  = (const float*)d_in[49];
  const float* c2v  = (const float*)d_in[50];
  const float* se2w1= (const float*)d_in[51];
  const float* se2w2= (const float*)d_in[52];
  const float* wc3  = (const float*)d_in[53];
  const float* bc3  = (const float*)d_in[54];
  const float* c3g  = (const float*)d_in[55];
  const float* c3b  = (const float*)d_in[56];
  const float* c3m  = (const float*)d_in[57];
  const float* c3v  = (const float*)d_in[58];
  const float* eps1 = (const float*)d_in[59];
  const float* eps2 = (const float*)d_in[60];

  float* ws = (float*)d_ws;
  float* part = ws + OFF_GX;   // gates_x region reused after lstm

  prep_kernel<<<2446, 256, 0, stream>>>(we1, be1, e1g,e1b,e1m,e1v,
      we2, be2,e2g,e2b,e2m,e2v, wih,whh,bih,bhh,
      bc1,c1g,c1b,c1m,c1v, bc2,c2g,c2b,c2m,c2v, bc3,c3g,c3b,c3m,c3v, ws);

  encoder_kernel<<<256, 256, 0, stream>>>(x, ws+OFF_W1F, ws+OFF_B1F,
      ws+OFF_S2E, ws+OFF_B2E, (const bf16*)(ws+OFF_WE2B), ws+OFF_XSRC);

  gates_kernel<<<256, 256, 0, stream>>>(ws+OFF_XSRC, ws+OFF_WIHT, ws+OFF_BIASG, ws+OFF_GX);
  lstm_kernel<<<32, 128, 0, stream>>>(ws+OFF_GX, ws+OFF_WHHT, ws+OFF_HSEQ);

  hn_kernel<<<8192, 64, 0, stream>>>(ws+OFF_HSEQ, ws+OFF_HN);
  pc_kernel<<<256, 256, 0, stream>>>(ws+OFF_HN, ws+OFF_PCOL, ws+OFF_CCOL);
  cutcorr_kernel<<<32, 256, 0, stream>>>(ws+OFF_PCOL, ws+OFF_CCOL, ws+OFF_HSEQ,
      ws+OFF_LAST, ws+OFF_CORR, (int*)(ws+OFF_CUTS));

  feat_kernel<<<16, 256, 0, stream>>>(ws+OFF_CORR, ws+OFF_FEATA, 4096);
  kan_kernel<<<128, 256, 0, stream>>>(ws+OFF_FEATA, muW1, muW2, muB1, muB2, 128, 128, ws+OFF_MUO);
  kan_kernel<<<128, 256, 0, stream>>>(ws+OFF_FEATA, sdW1, sdW2, sdB1, sdB2, 128, 128, ws+OFF_STDO);
  zmix_kernel<<<16, 256, 0, stream>>>(ws+OFF_MUO, ws+OFF_STDO, eps1, ws+OFF_LAST, ws+OFF_XZ);
  feat_kernel<<<32, 256, 0, stream>>>(ws+OFF_XZ, ws+OFF_FEATB, 8192);
  kan_kernel<<<128, 256, 0, stream>>>(ws+OFF_FEATB, mcW1, mcW2, mcB1, mcB2, 256, 128, ws+OFF_MUCO);
  kan_kernel<<<128, 256, 0, stream>>>(ws+OFF_FEATB, scW1, scW2, scB1, scB2, 256, 128, ws+OFF_STDCO);

  // conv-SE branch (partials reuse dead gates_x region — must run after lstm)
  convp_kernel<256,8,128,8,2><<<dim3(32,8), 256, 0, stream>>>(x, wc1, part);
  sef_kernel<128,8,8><<<32, 128, 0, stream>>>(part, ws+OFF_EPI1S, ws+OFF_EPI1B, se1w1, se1w2, ws+OFF_XC1);
  convp_kernel<128,5,256,4,1><<<dim3(32,4), 256, 0, stream>>>(ws+OFF_XC1, wc2, part);
  sef_kernel<256,16,4><<<32, 256, 0, stream>>>(part, ws+OFF_EPI2S, ws+OFF_EPI2B, se2w1, se2w2, ws+OFF_XC2);
  convp_kernel<256,3,128,8,2><<<dim3(32,8), 256, 0, stream>>>(ws+OFF_XC2, wc3, part);
  mean3f_kernel<<<32, 128, 0, stream>>>(part, ws+OFF_EPI3S, ws+OFF_EPI3B, ws+OFF_X2F);

  xall_kernel<<<16, 256, 0, stream>>>(ws+OFF_MUCO, ws+OFF_STDCO, eps2, ws+OFF_X2F, ws+OFF_XALL);
  feat_kernel<<<32, 256, 0, stream>>>(ws+OFF_XALL, ws+OFF_FEATC, 8192);
  kan_kernel<<<10, 256, 0, stream>>>(ws+OFF_FEATC, fcW1, fcW2, fcB1, fcB2, 256, 10, (float*)d_out);
}

// Round 7
// 1906.552 us; speedup vs baseline: 2.0613x; 1.1293x over previous
//
#include <hip/hip_runtime.h>
#include <hip/hip_bf16.h>
#include <math.h>

typedef __hip_bfloat16 bf16;

#define DEV static __device__ __forceinline__

DEV float geluf(float x){ return 0.5f*x*(1.0f + erff(x*0.70710678118654752f)); }
DEV float sigmf(float x){ return 1.0f/(1.0f + __expf(-x)); }
DEV float softplusf(float x){ return (x > 15.f) ? x : log1pf(__expf(x)); }
DEV float tanhfast(float x){ float e = __expf(2.f*x); return fmaf(-2.f, 1.f/(e+1.f), 1.f); }

typedef __attribute__((ext_vector_type(8))) short v8s;   // 8 bf16 (4 VGPRs)
typedef __attribute__((ext_vector_type(4))) float v4f;   // 4 fp32 acc
typedef _Float16 f16;
typedef f16 h2 __attribute__((ext_vector_type(2)));

DEV float dot2f(h2 a, h2 b, float c){
#if __has_builtin(__builtin_amdgcn_fdot2)
  return __builtin_amdgcn_fdot2(a, b, c, false);
#else
  return fmaf((float)a.y, (float)b.y, fmaf((float)a.x, (float)b.x, c));
#endif
}

// ---------------- workspace layout (float offsets) ----------------
enum : size_t {
  OFF_W1F   = 0,        // 2048  folded enc conv1 weights (256x8)
  OFF_B1F   = 2048,     // 256
  OFF_S2E   = 2304,     // 64
  OFF_B2E   = 2368,     // 64
  OFF_WIHT  = 2432,     // 32768 w_ih^T (64x512)
  OFF_BIASG = 35200,    // 512   b_ih+b_hh
  OFF_WHHT  = 35712,    // whh packed f16 pairs: h2[64][512] (32768 slots)
  OFF_EPI1S = 101248,   // 128
  OFF_EPI1B = 101376,   // 128
  OFF_EPI2S = 101504,   // 256
  OFF_EPI2B = 101760,   // 256
  OFF_EPI3S = 102016,   // 128
  OFF_EPI3B = 102144,   // 128
  OFF_WE2B  = 102272,   // 262144 floats = 524288 bf16: we2 repacked [o][e][f]
  OFF_XSRC  = 364416,   // 524288 (B,T,64)
  OFF_GX    = 888704,   // 4194304 (B,T,512); reused as conv partial buffer after lstm
  OFF_HSEQ  = 5083008,  // 1048576 (B,T,128)
  OFF_HN    = 6131584,  // 1048576
  OFF_PCOL  = 7180160,  // 8192
  OFF_CCOL  = 7188352,  // 8192
  OFF_CUTS  = 7196544,  // 32 (int)
  OFF_LAST  = 7196576,  // 4096
  OFF_CORR  = 7200672,  // 4096
  OFF_FEATA = 7204768,  // 28672 (B,128,7)
  OFF_MUO   = 7233440,  // 4096
  OFF_STDO  = 7237536,  // 4096
  OFF_XZ    = 7241632,  // 8192 (B,256)
  OFF_FEATB = 7249824,  // 57344 (B,256,7)
  OFF_MUCO  = 7307168,  // 4096
  OFF_STDCO = 7311264,  // 4096
  OFF_XC1   = 7315360,  // 131072 (B,128,32)
  OFF_XC2   = 7446432,  // 262144 (B,256,32)
  OFF_XC3   = 7708576,  // 131072 (unused now)
  OFF_X2F   = 7839648,  // 4096
  OFF_XALL  = 7843744,  // 8192
  OFF_FEATC = 7851936,  // 57344
  WS_FLOATS = 7909280   // ~31.6 MB
};

// ---------------- prep: fold BN, transpose/pack LSTM weights, repack we2 ----------------
__global__ __launch_bounds__(256) void prep_kernel(
    const float* we1, const float* be1,
    const float* e1g, const float* e1b, const float* e1m, const float* e1v,
    const float* we2, const float* be2, const float* e2g, const float* e2b, const float* e2m, const float* e2v,
    const float* wih, const float* whh, const float* bih, const float* bhh,
    const float* bc1, const float* c1g, const float* c1b, const float* c1m, const float* c1v,
    const float* bc2, const float* c2g, const float* c2b, const float* c2m, const float* c2v,
    const float* bc3, const float* c3g, const float* c3b, const float* c3m, const float* c3v,
    float* ws)
{
  int idx = blockIdx.x*256 + threadIdx.x;
  if(idx < 2048){
    int o = idx>>3;
    float s = e1g[o] * rsqrtf(e1v[o] + 1e-5f);
    ws[OFF_W1F + idx] = we1[idx] * s;
  } else if(idx < 2304){
    int o = idx - 2048;
    float s = e1g[o] * rsqrtf(e1v[o] + 1e-5f);
    ws[OFF_B1F + o] = s*(be1[o] - e1m[o]) + e1b[o];
  } else if(idx < 2368){
    int e = idx - 2304;
    float s = e2g[e] * rsqrtf(e2v[e] + 1e-5f);
    ws[OFF_S2E + e] = s;
    ws[OFF_B2E + e] = s*(be2[e] - e2m[e]) + e2b[e];
  } else if(idx < 35136){
    int q = idx - 2368; int e = q>>9, g = q&511;
    ws[OFF_WIHT + q] = wih[g*64 + e];
  } else if(idx < 35648){
    int g = idx - 35136;
    ws[OFF_BIASG + g] = bih[g] + bhh[g];
  } else if(idx < 101184){
    int q = idx - 35648;
    if(q < 32768){
      int k2 = q>>9, g = q&511;
      h2 v;
      v.x = (f16)whh[g*128 + 2*k2];
      v.y = (f16)whh[g*128 + 2*k2 + 1];
      ((h2*)(ws + OFF_WHHT))[q] = v;
    }
  } else if(idx < 101312){
    int o = idx - 101184;
    float s = c1g[o] * rsqrtf(c1v[o] + 1e-3f);
    ws[OFF_EPI1S + o] = s;
    ws[OFF_EPI1B + o] = s*(bc1[o] - c1m[o]) + c1b[o];
  } else if(idx < 101568){
    int o = idx - 101312;
    float s = c2g[o] * rsqrtf(c2v[o] + 1e-3f);
    ws[OFF_EPI2S + o] = s;
    ws[OFF_EPI2B + o] = s*(bc2[o] - c2m[o]) + c2b[o];
  } else if(idx < 101696){
    int o = idx - 101568;
    float s = c3g[o] * rsqrtf(c3v[o] + 1e-3f);
    ws[OFF_EPI3S + o] = s;
    ws[OFF_EPI3B + o] = s*(bc3[o] - c3m[o]) + c3b[o];
  } else if(idx < 625984){
    // we2 repack: [e][o*32+f] f32 -> [o][e][f] bf16
    int q = idx - 101696;
    int o = q >> 11, rem = q & 2047;
    int e = rem >> 5, f = rem & 31;
    bf16* Wr = (bf16*)(ws + OFF_WE2B);
    Wr[q] = __float2bfloat16(we2[(size_t)e*8192 + o*32 + f]);
  }
}

// ---------------- encoder: conv1(1x8 SAME)+BN+GELU fused into bf16 MFMA GEMM ----------------
// grid 256 = (b 32) x (tg 8); M-tile = 32 t, N = 64 e, K = 64 chunks x (4o x 32f = 128)
__global__ __launch_bounds__(256,1) void encoder_kernel(
    const float* __restrict__ x, const float* __restrict__ w1f, const float* __restrict__ b1f,
    const float* __restrict__ s2e, const float* __restrict__ b2e,
    const bf16* __restrict__ Wr, float* __restrict__ x_src)
{
  __shared__ float xs[39*32];
  __shared__ float w1s[2048];
  __shared__ float b1s[256];
  __shared__ __align__(16) unsigned short At[2][32*136];   // [t][k], stride 136 (pad)
  __shared__ __align__(16) unsigned short Bt[2][4*2560];   // 4 sub-tiles [e][f], stride 40 (pad)

  int blk = blockIdx.x; int b = blk>>3; int t0 = (blk&7)*32;
  int tid = threadIdx.x;

  for(int i=tid;i<2048;i+=256) w1s[i] = w1f[i];
  b1s[tid] = b1f[tid];
  for(int i=tid;i<39*32;i+=256){
    int r=i>>5, f=i&31; int t=t0-3+r;
    xs[i] = (t>=0 && t<256) ? x[(b*256+t)*32+f] : 0.f;
  }
  __syncthreads();

  int f = tid & 31, tq = tid >> 5;
  int lane = tid & 63, w = tid >> 6;
  int wm = w & 1, wn = w >> 1;
  int m0 = wm*16, n0 = wn*32;
  int l15 = lane & 15, quad = lane >> 4;

  const v8s* Wv = (const v8s*)Wr;

  auto stage = [&](int cc, int buf){
    v8s bw[4];
    #pragma unroll
    for(int i=0;i<4;i++) bw[i] = Wv[cc*1024 + i*256 + tid];
    unsigned short aval[16];
    #pragma unroll
    for(int ol=0;ol<4;ol++){
      int o = cc*4 + ol;
      float wv[8];
      #pragma unroll
      for(int j=0;j<8;j++) wv[j] = w1s[o*8+j];
      float bb = b1s[o];
      #pragma unroll
      for(int i=0;i<4;i++){
        int tl = tq*4 + i;
        float c = bb;
        #pragma unroll
        for(int j=0;j<8;j++) c = fmaf(wv[j], xs[(tl+j)*32+f], c);
        aval[ol*4+i] = ((__hip_bfloat16_raw)__float2bfloat16(geluf(c))).x;
      }
    }
    #pragma unroll
    for(int ol=0;ol<4;ol++){
      #pragma unroll
      for(int i=0;i<4;i++)
        At[buf][(tq*4+i)*136 + ol*32 + f] = aval[ol*4+i];
    }
    #pragma unroll
    for(int i=0;i<4;i++){
      int j = i*256 + tid;
      int ol = j>>8, e = (j&255)>>2, f8 = j&3;
      *(v8s*)&Bt[buf][ol*2560 + e*40 + f8*8] = bw[i];
    }
  };

  stage(0, 0);
  __syncthreads();

  v4f acc0 = {0.f,0.f,0.f,0.f}, acc1 = {0.f,0.f,0.f,0.f};

  for(int c=0;c<64;c++){
    int p = c & 1, q = p ^ 1;
    if(c < 63) stage(c+1, q);
    #pragma unroll
    for(int ol=0;ol<4;ol++){
      v8s av = *(const v8s*)&At[p][(m0+l15)*136 + ol*32 + quad*8];
      v8s b0 = *(const v8s*)&Bt[p][ol*2560 + (n0+l15)*40 + quad*8];
      v8s b1 = *(const v8s*)&Bt[p][ol*2560 + (n0+16+l15)*40 + quad*8];
      acc0 = __builtin_amdgcn_mfma_f32_16x16x32_bf16(av, b0, acc0, 0, 0, 0);
      acc1 = __builtin_amdgcn_mfma_f32_16x16x32_bf16(av, b1, acc1, 0, 0, 0);
    }
    __syncthreads();
  }

  #pragma unroll
  for(int r=0;r<4;r++){
    int t = t0 + m0 + quad*4 + r;
    int e0 = n0 + l15;
    float v0 = geluf(s2e[e0]*acc0[r] + b2e[e0]);
    x_src[((size_t)(b*256+t))*64 + e0] = v0;
    int e1 = e0 + 16;
    float v1 = geluf(s2e[e1]*acc1[r] + b2e[e1]);
    x_src[((size_t)(b*256+t))*64 + e1] = v1;
  }
}

// ---------------- gates_x = x_src @ w_ih^T + bias ----------------
__global__ __launch_bounds__(256) void gates_kernel(
    const float* x_src, const float* wihT, const float* biasg, float* gx)
{
  __shared__ float xsh[32*64];
  int blk = blockIdx.x; int b = blk>>3, t0 = (blk&7)*32;
  int tid = threadIdx.x;
  for(int i=tid;i<2048;i+=256) xsh[i] = x_src[((size_t)b*256+t0)*64 + i];
  __syncthreads();
  int g0 = tid, g1 = tid + 256;
  float acc0[32], acc1[32];
  #pragma unroll
  for(int tt=0;tt<32;tt++){ acc0[tt]=0.f; acc1[tt]=0.f; }
  for(int e=0;e<64;e++){
    float w0 = wihT[e*512+g0], w1 = wihT[e*512+g1];
    #pragma unroll
    for(int tt=0;tt<32;tt++){
      float xv = xsh[tt*64+e];
      acc0[tt] = fmaf(xv, w0, acc0[tt]);
      acc1[tt] = fmaf(xv, w1, acc1[tt]);
    }
  }
  float bg0 = biasg[g0], bg1 = biasg[g1];
  #pragma unroll
  for(int tt=0;tt<32;tt++){
    gx[((size_t)b*256+t0+tt)*512 + g0] = acc0[tt] + bg0;
    gx[((size_t)b*256+t0+tt)*512 + g1] = acc1[tt] + bg1;
  }
}

// ---------------- LSTM: 32 blocks x 256 threads; thread t owns gates t and t+256 ----------------
// thread n<128: (i,g) of unit n; thread 128+n: (f,o) of unit n -> exchange f,o via LDS.
// weights: 2 x 64 h2 = 128 VGPRs (no spill). h f16 double-buffered LDS as typed h2 array;
// reads are plain h2 loads (uniform-broadcast ds_read_b32) - no vector punning.
__global__ __launch_bounds__(256,1) void lstm_kernel(
    const float* __restrict__ gates_x, const float* __restrict__ whh16f, float* __restrict__ hseq)
{
  __shared__ __align__(16) h2 hsh[2][64];
  __shared__ float fo_sh[256];
  int b = blockIdx.x, tt = threadIdx.x;
  const h2* W = (const h2*)whh16f;
  h2 w0[64], w1[64];
  #pragma unroll
  for(int k=0;k<64;k++){
    w0[k] = W[k*512 + tt];
    w1[k] = W[k*512 + 256 + tt];
  }
  int n = tt & 127;
  if(tt < 128) ((f16*)&hsh[0][0])[n] = (f16)0.f;
  float c = 0.f;
  const float* gx = gates_x + (size_t)b*256*512;
  float na0 = gx[tt], na1 = gx[256 + tt];
  __syncthreads();
  int p = 0;
  for(int t=0;t<256;t++){
    float a0 = na0, a1 = na1;
    if(t < 255){
      const float* gp = gx + (size_t)(t+1)*512;
      na0 = gp[tt]; na1 = gp[256 + tt];
    }
    #pragma unroll
    for(int kk=0;kk<64;kk++){
      h2 q = hsh[p][kk];
      a0 = dot2f(q, w0[kk], a0);
      a1 = dot2f(q, w1[kk], a1);
    }
    // tt<128: a0=i(n), a1=g(n);  tt>=128: a0=f(n), a1=o(n)
    if(tt >= 128){
      fo_sh[n]       = a0;
      fo_sh[128 + n] = a1;
    }
    __syncthreads();
    if(tt < 128){
      float iv = sigmf(a0);
      float gv = tanhfast(a1);
      float fv = sigmf(fo_sh[n]);
      float ov = sigmf(fo_sh[128 + n]);
      c = fv*c + iv*gv;
      float h = ov*tanhfast(c);
      ((f16*)&hsh[p^1][0])[n] = (f16)h;
      hseq[((size_t)b*256+t)*128 + n] = h;
    }
    __syncthreads();
    p ^= 1;
  }
}

// ---------------- row-normalize hidden ----------------
__global__ __launch_bounds__(64) void hn_kernel(const float* hseq, float* hn)
{
  size_t row = blockIdx.x; int lane = threadIdx.x;
  const float* hp = hseq + row*128;
  float v0 = hp[lane], v1 = hp[lane+64];
  float ss = v0*v0 + v1*v1;
  #pragma unroll
  for(int m=1;m<64;m<<=1) ss += __shfl_xor(ss, m, 64);
  float r = 1.f / fmaxf(sqrtf(ss), 1e-8f);
  hn[row*128 + lane]      = v0*r;
  hn[row*128 + 64 + lane] = v1*r;
}

// ---------------- cluster: per-column partial/full sums of symmetric sim ----------------
__global__ __launch_bounds__(256) void pc_kernel(const float* hn, float* pcol, float* ccol)
{
  int blk = blockIdx.x; int b = blk>>3, chunk = blk&7;
  int tid = threadIdx.x; int il = tid & 31, ts = tid >> 5;
  int i = chunk*32 + il;
  const float4* hb = (const float4*)(hn + (size_t)b*32768);
  float4 hi[32];
  #pragma unroll
  for(int r=0;r<32;r++) hi[r] = hb[(size_t)i*32 + r];
  float ps=0.f, cs=0.f;
  for(int t=ts*32; t<ts*32+32; t++){
    float dx=0.f, dy=0.f, dz=0.f, dw=0.f;
    #pragma unroll
    for(int r=0;r<32;r++){
      float4 hv = hb[(size_t)t*32 + r];
      dx = fmaf(hi[r].x, hv.x, dx);
      dy = fmaf(hi[r].y, hv.y, dy);
      dz = fmaf(hi[r].z, hv.z, dz);
      dw = fmaf(hi[r].w, hv.w, dw);
    }
    float dot = (dx+dy)+(dz+dw);
    float sim = (t==i) ? 0.f : expf(-5.5f*(1.0f - dot));
    cs += sim;
    if(t < i) ps += sim;
  }
  __shared__ float red[16][32];
  red[ts][il] = ps; red[8+ts][il] = cs;
  __syncthreads();
  if(tid < 32){
    float s=0.f;
    for(int r=0;r<8;r++) s += red[r][tid];
    pcol[b*256 + chunk*32 + tid] = s;
  } else if(tid < 64){
    int c2 = tid - 32; float s=0.f;
    for(int r=0;r<8;r++) s += red[8+r][c2];
    ccol[b*256 + chunk*32 + c2] = s;
  }
}

// ---------------- prefix + dist + argmax + corr/last ----------------
__global__ __launch_bounds__(256) void cutcorr_kernel(
    const float* pcol, const float* ccol, const float* hseq,
    float* last, float* corr, int* cuts)
{
  int b = blockIdx.x, tid = threadIdx.x;
  __shared__ float D[256], RC[256], dist[256];
  __shared__ int cutsh;
  if(tid == 0){
    float d=0.f, r=0.f;
    for(int i=0;i<256;i++){
      d += 2.f*pcol[b*256+i]; D[i]=d;
      r += ccol[b*256+i];     RC[i]=r;
    }
  }
  __syncthreads();
  float tot = RC[255];
  if(tid < 255){
    float Dv = D[tid], Rv = RC[tid];
    float i_f = (float)(tid+1), j_f = 256.f - i_f;
    dist[tid] = Dv/(i_f*i_f) + (tot - 2.f*Rv + Dv)/(j_f*j_f) - 2.f*(Rv - Dv)/(i_f*j_f);
  }
  __syncthreads();
  if(tid == 0){
    float best = dist[0]; int bi = 0;
    for(int i=1;i<255;i++) if(dist[i] > best){ best = dist[i]; bi = i; }
    cutsh = bi + 1; cuts[b] = cutsh;
  }
  __syncthreads();
  int cut = cutsh;
  int k = tid & 127, half = tid >> 7;
  float s = 0.f;
  for(int t=half; t<cut; t+=2) s += hseq[((size_t)b*256+t)*128 + k];
  __shared__ float partial[2][128];
  partial[half][k] = s;
  __syncthreads();
  if(tid < 128){
    corr[b*128+tid] = (partial[0][tid] + partial[1][tid]) / (float)cut;
    last[b*128+tid] = hseq[((size_t)b*256+255)*128 + tid];
  }
}

// ---------------- KAN features ----------------
__global__ __launch_bounds__(256) void feat_kernel(const float* xin, float* feat, int n)
{
  int idx = blockIdx.x*256 + threadIdx.x;
  if(idx >= n) return;
  float xv = xin[idx];
  float* fp = feat + (size_t)idx*7;
  fp[0]=xv;
  fp[1]=sinf(xv); fp[2]=sinf(2.f*xv); fp[3]=sinf(4.f*xv);
  fp[4]=cosf(xv); fp[5]=cosf(2.f*xv); fp[6]=cosf(4.f*xv);
}

// ---------------- generic KAN ----------------
__global__ __launch_bounds__(256) void kan_kernel(
    const float* feat, const float* W1, const float* W2, const float* B1, const float* B2,
    int din, int dout, float* outp)
{
  int j = blockIdx.x, tid = threadIdx.x;
  int h = tid & 31, isub = tid >> 5;
  float acc[32];
  #pragma unroll
  for(int b=0;b<32;b++) acc[b]=0.f;
  float accB2 = 0.f;
  for(int i=isub; i<din; i+=8){
    size_t base = ((size_t)(i*dout + j))*32 + h;
    const float* w1p = W1 + base*7;
    float w1v[7];
    #pragma unroll
    for(int f=0;f<7;f++) w1v[f] = w1p[f];
    float b1v = B1[base];
    float w2v = W2[base];
    if(h == 0) accB2 += B2[i*dout + j];
    const float* fp0 = feat + (size_t)i*7;
    #pragma unroll 4
    for(int b=0;b<32;b++){
      const float* fp = fp0 + (size_t)b*din*7;
      float hv = b1v;
      #pragma unroll
      for(int f=0;f<7;f++) hv = fmaf(fp[f], w1v[f], hv);
      float sv = hv / (1.f + __expf(-hv));   // silu
      acc[b] = fmaf(sv, w2v, acc[b]);
    }
  }
  #pragma unroll
  for(int m=1;m<64;m<<=1){
    #pragma unroll
    for(int b=0;b<32;b++) acc[b] += __shfl_xor(acc[b], m, 64);
    accB2 += __shfl_xor(accB2, m, 64);
  }
  __shared__ float part[4][32];
  __shared__ float partB2[4];
  int lane = tid & 63, wv = tid >> 6;
  if(lane == 0){
    #pragma unroll
    for(int b=0;b<32;b++) part[wv][b] = acc[b];
    partB2[wv] = accB2;
  }
  __syncthreads();
  if(tid < 32){
    int b = tid;
    float r = part[0][b]+part[1][b]+part[2][b]+part[3][b]
            + partB2[0]+partB2[1]+partB2[2]+partB2[3];
    outp[b*dout + j] = r;
  }
}

// ---------------- z / x_z, x1 / x_all mixers ----------------
__global__ __launch_bounds__(256) void zmix_kernel(
    const float* muo, const float* stdo, const float* eps1, const float* last, float* xz)
{
  int idx = blockIdx.x*256 + threadIdx.x;
  if(idx >= 4096) return;
  int b = idx >> 7, k = idx & 127;
  float z = muo[idx] + softplusf(stdo[idx] - 5.f)*eps1[idx];
  xz[b*256 + k]       = last[idx];
  xz[b*256 + 128 + k] = z;
}

__global__ __launch_bounds__(256) void xall_kernel(
    const float* muco, const float* stdco, const float* eps2, const float* x2f, float* xa)
{
  int idx = blockIdx.x*256 + threadIdx.x;
  if(idx >= 4096) return;
  int b = idx >> 7, k = idx & 127;
  xa[b*256 + k]       = muco[idx] + softplusf(stdco[idx] - 5.f)*eps2[idx];
  xa[b*256 + 128 + k] = x2f[idx];
}

// ---------------- causal conv1d partial sums (c-chunked, VALU-bound) ----------------
template<int CIN, int K, int COUT, int NCH, int LG>
__global__ __launch_bounds__(COUT*LG, 1) void convp_kernel(
    const float* __restrict__ xin, const float* __restrict__ w, float* __restrict__ part)
{
  constexpr int L = 32/LG;
  constexpr int CCH = CIN/NCH;
  __shared__ float xsh[CCH*32];
  int b = blockIdx.x, ch = blockIdx.y;
  int tid = threadIdx.x;
  for(int i=tid; i<CCH*32; i+=COUT*LG) xsh[i] = xin[((size_t)b*CIN + ch*CCH)*32 + i];
  __syncthreads();
  int o = tid / LG, lh = tid % LG;
  int l0 = lh*L;
  float acc[L];
  #pragma unroll
  for(int j=0;j<L;j++) acc[j]=0.f;
  const float* wrow = w + ((size_t)o*CIN + ch*CCH)*K;
  for(int c=0;c<CCH;c++){
    float wv[K];
    #pragma unroll
    for(int k=0;k<K;k++) wv[k] = wrow[c*K + k];
    float xr[L+K-1];
    #pragma unroll
    for(int i=0;i<L+K-1;i++){
      int li = l0 - (K-1) + i;
      xr[i] = (li>=0) ? xsh[c*32+li] : 0.f;
    }
    #pragma unroll
    for(int j=0;j<L;j++){
      #pragma unroll
      for(int k=0;k<K;k++) acc[j] = fmaf(xr[j+k], wv[k], acc[j]);
    }
  }
  float* pp = part + (((size_t)ch*32 + b)*COUT + o)*32 + l0;
  #pragma unroll
  for(int j=0;j<L;j++) pp[j] = acc[j];
}

// ---------------- SE fused with partial-reduce + BN + GELU ----------------
template<int C, int R, int NP>
__global__ __launch_bounds__(C,1) void sef_kernel(
    const float* __restrict__ part, const float* __restrict__ epi_s, const float* __restrict__ epi_b,
    const float* __restrict__ w1, const float* __restrict__ w2, float* __restrict__ out)
{
  __shared__ float mean[C];
  __shared__ float y1[R];
  int b = blockIdx.x, c = threadIdx.x;
  float g[32];
  #pragma unroll
  for(int l=0;l<32;l++) g[l]=0.f;
  for(int p=0;p<NP;p++){
    const float* pp = part + (((size_t)p*32 + b)*C + c)*32;
    #pragma unroll
    for(int l=0;l<32;l++) g[l] += pp[l];
  }
  float s = epi_s[c], bb = epi_b[c];
  float m = 0.f;
  #pragma unroll
  for(int l=0;l<32;l++){ g[l] = geluf(s*g[l]+bb); m += g[l]; }
  mean[c] = m*(1.f/32.f);
  __syncthreads();
  if(c < R){
    float t=0.f;
    for(int k=0;k<C;k++) t = fmaf(mean[k], w1[c*C+k], t);
    y1[c] = fmaxf(t,0.f);
  }
  __syncthreads();
  float t=0.f;
  #pragma unroll
  for(int k=0;k<R;k++) t = fmaf(y1[k], w2[c*R+k], t);
  float sc = sigmf(t);
  float* op = out + ((size_t)b*C + c)*32;
  #pragma unroll
  for(int l=0;l<32;l++) op[l] = g[l]*sc;
}

// ---------------- conv3 partial-reduce + BN + GELU + mean over l ----------------
__global__ __launch_bounds__(128,1) void mean3f_kernel(
    const float* __restrict__ part, const float* __restrict__ epi_s, const float* __restrict__ epi_b,
    float* __restrict__ x2f)
{
  int b = blockIdx.x, c = threadIdx.x;
  float g[32];
  #pragma unroll
  for(int l=0;l<32;l++) g[l]=0.f;
  for(int p=0;p<8;p++){
    const float* pp = part + (((size_t)p*32 + b)*128 + c)*32;
    #pragma unroll
    for(int l=0;l<32;l++) g[l] += pp[l];
  }
  float s = epi_s[c], bb = epi_b[c];
  float m = 0.f;
  #pragma unroll
  for(int l=0;l<32;l++) m += geluf(s*g[l]+bb);
  x2f[b*128 + c] = m*(1.f/32.f);
}

// ---------------- launch ----------------
extern "C" void kernel_launch(void* const* d_in, const int* in_sizes, int n_in,
                              void* d_out, int out_size, void* d_ws, size_t ws_size,
                              hipStream_t stream)
{
  const float* x    = (const float*)d_in[0];
  const float* we1  = (const float*)d_in[1];
  const float* be1  = (const float*)d_in[2];
  const float* e1g  = (const float*)d_in[3];
  const float* e1b  = (const float*)d_in[4];
  const float* e1m  = (const float*)d_in[5];
  const float* e1v  = (const float*)d_in[6];
  const float* we2  = (const float*)d_in[7];
  const float* be2  = (const float*)d_in[8];
  const float* e2g  = (const float*)d_in[9];
  const float* e2b  = (const float*)d_in[10];
  const float* e2m  = (const float*)d_in[11];
  const float* e2v  = (const float*)d_in[12];
  const float* wih  = (const float*)d_in[13];
  const float* whh  = (const float*)d_in[14];
  const float* bih  = (const float*)d_in[15];
  const float* bhh  = (const float*)d_in[16];
  const float* muW1 = (const float*)d_in[17];
  const float* muW2 = (const float*)d_in[18];
  const float* muB1 = (const float*)d_in[19];
  const float* muB2 = (const float*)d_in[20];
  const float* sdW1 = (const float*)d_in[21];
  const float* sdW2 = (const float*)d_in[22];
  const float* sdB1 = (const float*)d_in[23];
  const float* sdB2 = (const float*)d_in[24];
  const float* mcW1 = (const float*)d_in[25];
  const float* mcW2 = (const float*)d_in[26];
  const float* mcB1 = (const float*)d_in[27];
  const float* mcB2 = (const float*)d_in[28];
  const float* scW1 = (const float*)d_in[29];
  const float* scW2 = (const float*)d_in[30];
  const float* scB1 = (const float*)d_in[31];
  const float* scB2 = (const float*)d_in[32];
  const float* fcW1 = (const float*)d_in[33];
  const float* fcW2 = (const float*)d_in[34];
  const float* fcB1 = (const float*)d_in[35];
  const float* fcB2 = (const float*)d_in[36];
  const float* wc1  = (const float*)d_in[37];
  const float* bc1  = (const float*)d_in[38];
  const float* c1g  = (const float*)d_in[39];
  const float* c1b  = (const float*)d_in[40];
  const float* c1m  = (const float*)d_in[41];
  const float* c1v  = (const float*)d_in[42];
  const float* se1w1= (const float*)d_in[43];
  const float* se1w2= (const float*)d_in[44];
  const float* wc2  = (const float*)d_in[45];
  const float* bc2  = (const float*)d_in[46];
  const float* c2g  = (const float*)d_in[47];
  const float* c2b  = (const float*)d_in[48];
  const float* c2m  = (const float*)d_in[49];
  const float* c2v  = (const float*)d_in[50];
  const float* se2w1= (const float*)d_in[51];
  const float* se2w2= (const float*)d_in[52];
  const float* wc3  = (const float*)d_in[53];
  const float* bc3  = (const float*)d_in[54];
  const float* c3g  = (const float*)d_in[55];
  const float* c3b  = (const float*)d_in[56];
  const float* c3m  = (const float*)d_in[57];
  const float* c3v  = (const float*)d_in[58];
  const float* eps1 = (const float*)d_in[59];
  const float* eps2 = (const float*)d_in[60];

  float* ws = (float*)d_ws;
  float* part = ws + OFF_GX;   // gates_x region reused after lstm

  prep_kernel<<<2446, 256, 0, stream>>>(we1, be1, e1g,e1b,e1m,e1v,
      we2, be2,e2g,e2b,e2m,e2v, wih,whh,bih,bhh,
      bc1,c1g,c1b,c1m,c1v, bc2,c2g,c2b,c2m,c2v, bc3,c3g,c3b,c3m,c3v, ws);

  encoder_kernel<<<256, 256, 0, stream>>>(x, ws+OFF_W1F, ws+OFF_B1F,
      ws+OFF_S2E, ws+OFF_B2E, (const bf16*)(ws+OFF_WE2B), ws+OFF_XSRC);

  gates_kernel<<<256, 256, 0, stream>>>(ws+OFF_XSRC, ws+OFF_WIHT, ws+OFF_BIASG, ws+OFF_GX);
  lstm_kernel<<<32, 256, 0, stream>>>(ws+OFF_GX, ws+OFF_WHHT, ws+OFF_HSEQ);

  hn_kernel<<<8192, 64, 0, stream>>>(ws+OFF_HSEQ, ws+OFF_HN);
  pc_kernel<<<256, 256, 0, stream>>>(ws+OFF_HN, ws+OFF_PCOL, ws+OFF_CCOL);
  cutcorr_kernel<<<32, 256, 0, stream>>>(ws+OFF_PCOL, ws+OFF_CCOL, ws+OFF_HSEQ,
      ws+OFF_LAST, ws+OFF_CORR, (int*)(ws+OFF_CUTS));

  feat_kernel<<<16, 256, 0, stream>>>(ws+OFF_CORR, ws+OFF_FEATA, 4096);
  kan_kernel<<<128, 256, 0, stream>>>(ws+OFF_FEATA, muW1, muW2, muB1, muB2, 128, 128, ws+OFF_MUO);
  kan_kernel<<<128, 256, 0, stream>>>(ws+OFF_FEATA, sdW1, sdW2, sdB1, sdB2, 128, 128, ws+OFF_STDO);
  zmix_kernel<<<16, 256, 0, stream>>>(ws+OFF_MUO, ws+OFF_STDO, eps1, ws+OFF_LAST, ws+OFF_XZ);
  feat_kernel<<<32, 256, 0, stream>>>(ws+OFF_XZ, ws+OFF_FEATB, 8192);
  kan_kernel<<<128, 256, 0, stream>>>(ws+OFF_FEATB, mcW1, mcW2, mcB1, mcB2, 256, 128, ws+OFF_MUCO);
  kan_kernel<<<128, 256, 0, stream>>>(ws+OFF_FEATB, scW1, scW2, scB1, scB2, 256, 128, ws+OFF_STDCO);

  convp_kernel<256,8,128,8,2><<<dim3(32,8), 256, 0, stream>>>(x, wc1, part);
  sef_kernel<128,8,8><<<32, 128, 0, stream>>>(part, ws+OFF_EPI1S, ws+OFF_EPI1B, se1w1, se1w2, ws+OFF_XC1);
  convp_kernel<128,5,256,4,1><<<dim3(32,4), 256, 0, stream>>>(ws+OFF_XC1, wc2, part);
  sef_kernel<256,16,4><<<32, 256, 0, stream>>>(part, ws+OFF_EPI2S, ws+OFF_EPI2B, se2w1, se2w2, ws+OFF_XC2);
  convp_kernel<256,3,128,8,2><<<dim3(32,8), 256, 0, stream>>>(ws+OFF_XC2, wc3, part);
  mean3f_kernel<<<32, 128, 0, stream>>>(part, ws+OFF_EPI3S, ws+OFF_EPI3B, ws+OFF_X2F);

  xall_kernel<<<16, 256, 0, stream>>>(ws+OFF_MUCO, ws+OFF_STDCO, eps2, ws+OFF_X2F, ws+OFF_XALL);
  feat_kernel<<<32, 256, 0, stream>>>(ws+OFF_XALL, ws+OFF_FEATC, 8192);
  kan_kernel<<<10, 256, 0, stream>>>(ws+OFF_FEATC, fcW1, fcW2, fcB1, fcB2, 256, 10, (float*)d_out);
}

// Round 8
// 980.896 us; speedup vs baseline: 4.0065x; 1.9437x over previous
//
#include <hip/hip_runtime.h>
#include <hip/hip_bf16.h>
#include <math.h>

typedef __hip_bfloat16 bf16;

#define DEV static __device__ __forceinline__

DEV float geluf(float x){ return 0.5f*x*(1.0f + erff(x*0.70710678118654752f)); }
DEV float sigmf(float x){ return 1.0f/(1.0f + __expf(-x)); }
DEV float softplusf(float x){ return (x > 15.f) ? x : log1pf(__expf(x)); }
DEV float tanhfast(float x){ float e = __expf(2.f*x); return fmaf(-2.f, 1.f/(e+1.f), 1.f); }

typedef __attribute__((ext_vector_type(8))) short v8s;   // 8 bf16 (4 VGPRs)
typedef __attribute__((ext_vector_type(4))) float v4f;   // 4 fp32 acc
typedef _Float16 f16;
typedef f16 h2 __attribute__((ext_vector_type(2)));

DEV float dot2f(h2 a, h2 b, float c){
#if __has_builtin(__builtin_amdgcn_fdot2)
  return __builtin_amdgcn_fdot2(a, b, c, false);
#else
  return fmaf((float)a.y, (float)b.y, fmaf((float)a.x, (float)b.x, c));
#endif
}

// ---------------- workspace layout (float offsets) ----------------
enum : size_t {
  OFF_W1F   = 0,        // 2048  folded enc conv1 weights (256x8)
  OFF_B1F   = 2048,     // 256
  OFF_S2E   = 2304,     // 64
  OFF_B2E   = 2368,     // 64
  OFF_WIHT  = 2432,     // 32768 w_ih^T (64x512)
  OFF_BIASG = 35200,    // 512   b_ih+b_hh
  OFF_WHHT  = 35712,    // whh packed f16 pairs: h2[64][512] (32768 slots)
  OFF_EPI1S = 101248,   // 128
  OFF_EPI1B = 101376,   // 128
  OFF_EPI2S = 101504,   // 256
  OFF_EPI2B = 101760,   // 256
  OFF_EPI3S = 102016,   // 128
  OFF_EPI3B = 102144,   // 128
  OFF_WE2B  = 102272,   // 262144 floats = 524288 bf16: we2 repacked [o][e][f]
  OFF_XSRC  = 364416,   // 524288 (B,T,64)
  OFF_GX    = 888704,   // 4194304 (B,T,512); reused as conv partial buffer after lstm
  OFF_HSEQ  = 5083008,  // 1048576 (B,T,128)
  OFF_HN    = 6131584,  // 1048576
  OFF_PCOL  = 7180160,  // 8192
  OFF_CCOL  = 7188352,  // 8192
  OFF_CUTS  = 7196544,  // 32 (int)
  OFF_LAST  = 7196576,  // 4096
  OFF_CORR  = 7200672,  // 4096
  OFF_FEATA = 7204768,  // 28672 (B,128,7)
  OFF_MUO   = 7233440,  // 4096
  OFF_STDO  = 7237536,  // 4096
  OFF_XZ    = 7241632,  // 8192 (B,256)
  OFF_FEATB = 7249824,  // 57344 (B,256,7)
  OFF_MUCO  = 7307168,  // 4096
  OFF_STDCO = 7311264,  // 4096
  OFF_XC1   = 7315360,  // 131072 (B,128,32)
  OFF_XC2   = 7446432,  // 262144 (B,256,32)
  OFF_KP    = 7708576,  // 32768 kan i-chunk partials (old XC3, dead)
  OFF_B2S   = 7741344,  // 522: per-kan sum_i B2[i][j]: mu+0,std+128,muc+256,stdc+384,fc+512
  OFF_X2F   = 7839648,  // 4096
  OFF_XALL  = 7843744,  // 8192
  OFF_FEATC = 7851936,  // 57344
  WS_FLOATS = 7909280   // ~31.6 MB
};

// ---------------- prep: fold BN, transpose/pack LSTM weights, repack we2, B2 sums ----------------
__global__ __launch_bounds__(256) void prep_kernel(
    const float* we1, const float* be1,
    const float* e1g, const float* e1b, const float* e1m, const float* e1v,
    const float* we2, const float* be2, const float* e2g, const float* e2b, const float* e2m, const float* e2v,
    const float* wih, const float* whh, const float* bih, const float* bhh,
    const float* bc1, const float* c1g, const float* c1b, const float* c1m, const float* c1v,
    const float* bc2, const float* c2g, const float* c2b, const float* c2m, const float* c2v,
    const float* bc3, const float* c3g, const float* c3b, const float* c3m, const float* c3v,
    const float* muB2, const float* sdB2, const float* mcB2, const float* scB2, const float* fcB2,
    float* ws)
{
  int idx = blockIdx.x*256 + threadIdx.x;
  if(idx < 2048){
    int o = idx>>3;
    float s = e1g[o] * rsqrtf(e1v[o] + 1e-5f);
    ws[OFF_W1F + idx] = we1[idx] * s;
  } else if(idx < 2304){
    int o = idx - 2048;
    float s = e1g[o] * rsqrtf(e1v[o] + 1e-5f);
    ws[OFF_B1F + o] = s*(be1[o] - e1m[o]) + e1b[o];
  } else if(idx < 2368){
    int e = idx - 2304;
    float s = e2g[e] * rsqrtf(e2v[e] + 1e-5f);
    ws[OFF_S2E + e] = s;
    ws[OFF_B2E + e] = s*(be2[e] - e2m[e]) + e2b[e];
  } else if(idx < 35136){
    int q = idx - 2368; int e = q>>9, g = q&511;
    ws[OFF_WIHT + q] = wih[g*64 + e];
  } else if(idx < 35648){
    int g = idx - 35136;
    ws[OFF_BIASG + g] = bih[g] + bhh[g];
  } else if(idx < 101184){
    int q = idx - 35648;
    if(q < 32768){
      int k2 = q>>9, g = q&511;
      h2 v;
      v.x = (f16)whh[g*128 + 2*k2];
      v.y = (f16)whh[g*128 + 2*k2 + 1];
      ((h2*)(ws + OFF_WHHT))[q] = v;
    }
  } else if(idx < 101312){
    int o = idx - 101184;
    float s = c1g[o] * rsqrtf(c1v[o] + 1e-3f);
    ws[OFF_EPI1S + o] = s;
    ws[OFF_EPI1B + o] = s*(bc1[o] - c1m[o]) + c1b[o];
  } else if(idx < 101568){
    int o = idx - 101312;
    float s = c2g[o] * rsqrtf(c2v[o] + 1e-3f);
    ws[OFF_EPI2S + o] = s;
    ws[OFF_EPI2B + o] = s*(bc2[o] - c2m[o]) + c2b[o];
  } else if(idx < 101696){
    int o = idx - 101568;
    float s = c3g[o] * rsqrtf(c3v[o] + 1e-3f);
    ws[OFF_EPI3S + o] = s;
    ws[OFF_EPI3B + o] = s*(bc3[o] - c3m[o]) + c3b[o];
  } else if(idx < 625984){
    // we2 repack: [e][o*32+f] f32 -> [o][e][f] bf16
    int q = idx - 101696;
    int o = q >> 11, rem = q & 2047;
    int e = rem >> 5, f = rem & 31;
    bf16* Wr = (bf16*)(ws + OFF_WE2B);
    Wr[q] = __float2bfloat16(we2[(size_t)e*8192 + o*32 + f]);
  } else if(idx < 626112){
    int j = idx - 625984; float s = 0.f;
    for(int i=0;i<128;i++) s += muB2[i*128+j];
    ws[OFF_B2S + j] = s;
  } else if(idx < 626240){
    int j = idx - 626112; float s = 0.f;
    for(int i=0;i<128;i++) s += sdB2[i*128+j];
    ws[OFF_B2S + 128 + j] = s;
  } else if(idx < 626368){
    int j = idx - 626240; float s = 0.f;
    for(int i=0;i<256;i++) s += mcB2[i*128+j];
    ws[OFF_B2S + 256 + j] = s;
  } else if(idx < 626496){
    int j = idx - 626368; float s = 0.f;
    for(int i=0;i<256;i++) s += scB2[i*128+j];
    ws[OFF_B2S + 384 + j] = s;
  } else if(idx < 626506){
    int j = idx - 626496; float s = 0.f;
    for(int i=0;i<256;i++) s += fcB2[i*10+j];
    ws[OFF_B2S + 512 + j] = s;
  }
}

// ---------------- encoder: conv1(1x8 SAME)+BN+GELU fused into bf16 MFMA GEMM ----------------
// grid 256 = (b 32) x (tg 8); M-tile = 32 t, N = 64 e, K = 64 chunks x (4o x 32f = 128)
__global__ __launch_bounds__(256,1) void encoder_kernel(
    const float* __restrict__ x, const float* __restrict__ w1f, const float* __restrict__ b1f,
    const float* __restrict__ s2e, const float* __restrict__ b2e,
    const bf16* __restrict__ Wr, float* __restrict__ x_src)
{
  __shared__ float xs[39*32];
  __shared__ float w1s[2048];
  __shared__ float b1s[256];
  __shared__ __align__(16) unsigned short At[2][32*136];   // [t][k], stride 136 (pad)
  __shared__ __align__(16) unsigned short Bt[2][4*2560];   // 4 sub-tiles [e][f], stride 40 (pad)

  int blk = blockIdx.x; int b = blk>>3; int t0 = (blk&7)*32;
  int tid = threadIdx.x;

  for(int i=tid;i<2048;i+=256) w1s[i] = w1f[i];
  b1s[tid] = b1f[tid];
  for(int i=tid;i<39*32;i+=256){
    int r=i>>5, f=i&31; int t=t0-3+r;
    xs[i] = (t>=0 && t<256) ? x[(b*256+t)*32+f] : 0.f;
  }
  __syncthreads();

  int f = tid & 31, tq = tid >> 5;
  int lane = tid & 63, w = tid >> 6;
  int wm = w & 1, wn = w >> 1;
  int m0 = wm*16, n0 = wn*32;
  int l15 = lane & 15, quad = lane >> 4;

  const v8s* Wv = (const v8s*)Wr;

  auto stage = [&](int cc, int buf){
    v8s bw[4];
    #pragma unroll
    for(int i=0;i<4;i++) bw[i] = Wv[cc*1024 + i*256 + tid];
    unsigned short aval[16];
    #pragma unroll
    for(int ol=0;ol<4;ol++){
      int o = cc*4 + ol;
      float wv[8];
      #pragma unroll
      for(int j=0;j<8;j++) wv[j] = w1s[o*8+j];
      float bb = b1s[o];
      #pragma unroll
      for(int i=0;i<4;i++){
        int tl = tq*4 + i;
        float c = bb;
        #pragma unroll
        for(int j=0;j<8;j++) c = fmaf(wv[j], xs[(tl+j)*32+f], c);
        aval[ol*4+i] = ((__hip_bfloat16_raw)__float2bfloat16(geluf(c))).x;
      }
    }
    #pragma unroll
    for(int ol=0;ol<4;ol++){
      #pragma unroll
      for(int i=0;i<4;i++)
        At[buf][(tq*4+i)*136 + ol*32 + f] = aval[ol*4+i];
    }
    #pragma unroll
    for(int i=0;i<4;i++){
      int j = i*256 + tid;
      int ol = j>>8, e = (j&255)>>2, f8 = j&3;
      *(v8s*)&Bt[buf][ol*2560 + e*40 + f8*8] = bw[i];
    }
  };

  stage(0, 0);
  __syncthreads();

  v4f acc0 = {0.f,0.f,0.f,0.f}, acc1 = {0.f,0.f,0.f,0.f};

  for(int c=0;c<64;c++){
    int p = c & 1, q = p ^ 1;
    if(c < 63) stage(c+1, q);
    #pragma unroll
    for(int ol=0;ol<4;ol++){
      v8s av = *(const v8s*)&At[p][(m0+l15)*136 + ol*32 + quad*8];
      v8s b0 = *(const v8s*)&Bt[p][ol*2560 + (n0+l15)*40 + quad*8];
      v8s b1 = *(const v8s*)&Bt[p][ol*2560 + (n0+16+l15)*40 + quad*8];
      acc0 = __builtin_amdgcn_mfma_f32_16x16x32_bf16(av, b0, acc0, 0, 0, 0);
      acc1 = __builtin_amdgcn_mfma_f32_16x16x32_bf16(av, b1, acc1, 0, 0, 0);
    }
    __syncthreads();
  }

  #pragma unroll
  for(int r=0;r<4;r++){
    int t = t0 + m0 + quad*4 + r;
    int e0 = n0 + l15;
    float v0 = geluf(s2e[e0]*acc0[r] + b2e[e0]);
    x_src[((size_t)(b*256+t))*64 + e0] = v0;
    int e1 = e0 + 16;
    float v1 = geluf(s2e[e1]*acc1[r] + b2e[e1]);
    x_src[((size_t)(b*256+t))*64 + e1] = v1;
  }
}

// ---------------- gates_x = x_src @ w_ih^T + bias ----------------
__global__ __launch_bounds__(256) void gates_kernel(
    const float* x_src, const float* wihT, const float* biasg, float* gx)
{
  __shared__ float xsh[32*64];
  int blk = blockIdx.x; int b = blk>>3, t0 = (blk&7)*32;
  int tid = threadIdx.x;
  for(int i=tid;i<2048;i+=256) xsh[i] = x_src[((size_t)b*256+t0)*64 + i];
  __syncthreads();
  int g0 = tid, g1 = tid + 256;
  float acc0[32], acc1[32];
  #pragma unroll
  for(int tt=0;tt<32;tt++){ acc0[tt]=0.f; acc1[tt]=0.f; }
  for(int e=0;e<64;e++){
    float w0 = wihT[e*512+g0], w1 = wihT[e*512+g1];
    #pragma unroll
    for(int tt=0;tt<32;tt++){
      float xv = xsh[tt*64+e];
      acc0[tt] = fmaf(xv, w0, acc0[tt]);
      acc1[tt] = fmaf(xv, w1, acc1[tt]);
    }
  }
  float bg0 = biasg[g0], bg1 = biasg[g1];
  #pragma unroll
  for(int tt=0;tt<32;tt++){
    gx[((size_t)b*256+t0+tt)*512 + g0] = acc0[tt] + bg0;
    gx[((size_t)b*256+t0+tt)*512 + g1] = acc1[tt] + bg1;
  }
}

// ---------------- LSTM: 32 blocks x 256 threads; thread t owns gates t and t+256 ----------------
__global__ __launch_bounds__(256,1) void lstm_kernel(
    const float* __restrict__ gates_x, const float* __restrict__ whh16f, float* __restrict__ hseq)
{
  __shared__ __align__(16) h2 hsh[2][64];
  __shared__ float fo_sh[256];
  int b = blockIdx.x, tt = threadIdx.x;
  const h2* W = (const h2*)whh16f;
  h2 w0[64], w1[64];
  #pragma unroll
  for(int k=0;k<64;k++){
    w0[k] = W[k*512 + tt];
    w1[k] = W[k*512 + 256 + tt];
  }
  int n = tt & 127;
  if(tt < 128) ((f16*)&hsh[0][0])[n] = (f16)0.f;
  float c = 0.f;
  const float* gx = gates_x + (size_t)b*256*512;
  float na0 = gx[tt], na1 = gx[256 + tt];
  __syncthreads();
  int p = 0;
  for(int t=0;t<256;t++){
    float a0 = na0, a1 = na1;
    if(t < 255){
      const float* gp = gx + (size_t)(t+1)*512;
      na0 = gp[tt]; na1 = gp[256 + tt];
    }
    #pragma unroll
    for(int kk=0;kk<64;kk++){
      h2 q = hsh[p][kk];
      a0 = dot2f(q, w0[kk], a0);
      a1 = dot2f(q, w1[kk], a1);
    }
    if(tt >= 128){
      fo_sh[n]       = a0;
      fo_sh[128 + n] = a1;
    }
    __syncthreads();
    if(tt < 128){
      float iv = sigmf(a0);
      float gv = tanhfast(a1);
      float fv = sigmf(fo_sh[n]);
      float ov = sigmf(fo_sh[128 + n]);
      c = fv*c + iv*gv;
      float h = ov*tanhfast(c);
      ((f16*)&hsh[p^1][0])[n] = (f16)h;
      hseq[((size_t)b*256+t)*128 + n] = h;
    }
    __syncthreads();
    p ^= 1;
  }
}

// ---------------- row-normalize hidden ----------------
__global__ __launch_bounds__(64) void hn_kernel(const float* hseq, float* hn)
{
  size_t row = blockIdx.x; int lane = threadIdx.x;
  const float* hp = hseq + row*128;
  float v0 = hp[lane], v1 = hp[lane+64];
  float ss = v0*v0 + v1*v1;
  #pragma unroll
  for(int m=1;m<64;m<<=1) ss += __shfl_xor(ss, m, 64);
  float r = 1.f / fmaxf(sqrtf(ss), 1e-8f);
  hn[row*128 + lane]      = v0*r;
  hn[row*128 + 64 + lane] = v1*r;
}

// ---------------- cluster: per-column partial/full sums of symmetric sim ----------------
__global__ __launch_bounds__(256) void pc_kernel(const float* hn, float* pcol, float* ccol)
{
  int blk = blockIdx.x; int b = blk>>3, chunk = blk&7;
  int tid = threadIdx.x; int il = tid & 31, ts = tid >> 5;
  int i = chunk*32 + il;
  const float4* hb = (const float4*)(hn + (size_t)b*32768);
  float4 hi[32];
  #pragma unroll
  for(int r=0;r<32;r++) hi[r] = hb[(size_t)i*32 + r];
  float ps=0.f, cs=0.f;
  for(int t=ts*32; t<ts*32+32; t++){
    float dx=0.f, dy=0.f, dz=0.f, dw=0.f;
    #pragma unroll
    for(int r=0;r<32;r++){
      float4 hv = hb[(size_t)t*32 + r];
      dx = fmaf(hi[r].x, hv.x, dx);
      dy = fmaf(hi[r].y, hv.y, dy);
      dz = fmaf(hi[r].z, hv.z, dz);
      dw = fmaf(hi[r].w, hv.w, dw);
    }
    float dot = (dx+dy)+(dz+dw);
    float sim = (t==i) ? 0.f : expf(-5.5f*(1.0f - dot));
    cs += sim;
    if(t < i) ps += sim;
  }
  __shared__ float red[16][32];
  red[ts][il] = ps; red[8+ts][il] = cs;
  __syncthreads();
  if(tid < 32){
    float s=0.f;
    for(int r=0;r<8;r++) s += red[r][tid];
    pcol[b*256 + chunk*32 + tid] = s;
  } else if(tid < 64){
    int c2 = tid - 32; float s=0.f;
    for(int r=0;r<8;r++) s += red[8+r][c2];
    ccol[b*256 + chunk*32 + c2] = s;
  }
}

// ---------------- prefix + dist + argmax + corr/last ----------------
__global__ __launch_bounds__(256) void cutcorr_kernel(
    const float* pcol, const float* ccol, const float* hseq,
    float* last, float* corr, int* cuts)
{
  int b = blockIdx.x, tid = threadIdx.x;
  __shared__ float D[256], RC[256], dist[256];
  __shared__ int cutsh;
  if(tid == 0){
    float d=0.f, r=0.f;
    for(int i=0;i<256;i++){
      d += 2.f*pcol[b*256+i]; D[i]=d;
      r += ccol[b*256+i];     RC[i]=r;
    }
  }
  __syncthreads();
  float tot = RC[255];
  if(tid < 255){
    float Dv = D[tid], Rv = RC[tid];
    float i_f = (float)(tid+1), j_f = 256.f - i_f;
    dist[tid] = Dv/(i_f*i_f) + (tot - 2.f*Rv + Dv)/(j_f*j_f) - 2.f*(Rv - Dv)/(i_f*j_f);
  }
  __syncthreads();
  if(tid == 0){
    float best = dist[0]; int bi = 0;
    for(int i=1;i<255;i++) if(dist[i] > best){ best = dist[i]; bi = i; }
    cutsh = bi + 1; cuts[b] = cutsh;
  }
  __syncthreads();
  int cut = cutsh;
  int k = tid & 127, half = tid >> 7;
  float s = 0.f;
  for(int t=half; t<cut; t+=2) s += hseq[((size_t)b*256+t)*128 + k];
  __shared__ float partial[2][128];
  partial[half][k] = s;
  __syncthreads();
  if(tid < 128){
    corr[b*128+tid] = (partial[0][tid] + partial[1][tid]) / (float)cut;
    last[b*128+tid] = hseq[((size_t)b*256+255)*128 + tid];
  }
}

// ---------------- KAN features ----------------
__global__ __launch_bounds__(256) void feat_kernel(const float* xin, float* feat, int n)
{
  int idx = blockIdx.x*256 + threadIdx.x;
  if(idx >= n) return;
  float xv = xin[idx];
  float* fp = feat + (size_t)idx*7;
  fp[0]=xv;
  fp[1]=sinf(xv); fp[2]=sinf(2.f*xv); fp[3]=sinf(4.f*xv);
  fp[4]=cosf(xv); fp[5]=cosf(2.f*xv); fp[6]=cosf(4.f*xv);
}

// ---------------- KAN i-chunk partial: grid (dout, din/32), block 256 = 8 hg x 32 b ----------------
// feat staged in LDS (row stride 225: 224%32==0 would be 32-way bank conflict);
// W1/B1/W2 streamed as contiguous float4 (28/4/4 floats per (i,hg)), each byte read once.
__global__ __launch_bounds__(256) void kanp_kernel(
    const float* __restrict__ feat, const float* __restrict__ W1,
    const float* __restrict__ B1, const float* __restrict__ W2,
    int din, int dout, float* __restrict__ partial)
{
  __shared__ float feat_s[32*225];
  __shared__ float red[8][32];
  int j = blockIdx.x, ic = blockIdx.y;
  int i0 = ic*32;
  int tid = threadIdx.x;
  int b = tid & 31, hg = tid >> 5;
  for(int q=tid; q<1792; q+=256){
    int br = q/56, qq = q - br*56;
    float4 v = *(const float4*)(feat + ((size_t)br*din + i0)*7 + qq*4);
    float* d = &feat_s[br*225 + qq*4];
    d[0]=v.x; d[1]=v.y; d[2]=v.z; d[3]=v.w;
  }
  __syncthreads();
  float acc = 0.f;
  const float* fb = &feat_s[b*225];
  for(int ii=0; ii<32; ii++){
    int i = i0 + ii;
    size_t hbase = ((size_t)i*dout + j)*32 + hg*4;
    const float4* w1p = (const float4*)(W1 + ((size_t)i*dout + j)*224 + hg*28);
    float w1a[28];
    #pragma unroll
    for(int q=0;q<7;q++) *(float4*)&w1a[q*4] = w1p[q];
    float4 b1v = *(const float4*)(B1 + hbase);
    float4 w2v = *(const float4*)(W2 + hbase);
    float f[7];
    #pragma unroll
    for(int q=0;q<7;q++) f[q] = fb[ii*7+q];
    float b1a[4] = {b1v.x, b1v.y, b1v.z, b1v.w};
    float w2a[4] = {w2v.x, w2v.y, w2v.z, w2v.w};
    #pragma unroll
    for(int hh=0;hh<4;hh++){
      float hv = b1a[hh];
      #pragma unroll
      for(int q=0;q<7;q++) hv = fmaf(f[q], w1a[hh*7+q], hv);
      float sv = hv / (1.f + __expf(-hv));   // silu
      acc = fmaf(sv, w2a[hh], acc);
    }
  }
  red[hg][b] = acc;
  __syncthreads();
  if(tid < 32){
    float s = 0.f;
    #pragma unroll
    for(int q=0;q<8;q++) s += red[q][tid];
    partial[((size_t)ic*32 + tid)*dout + j] = s;
  }
}

// ---------------- KAN reduce over i-chunks + B2 sum ----------------
__global__ __launch_bounds__(256) void kanr_kernel(
    const float* __restrict__ partial, const float* __restrict__ b2s,
    int NI, int dout, float* __restrict__ outp)
{
  int idx = blockIdx.x*256 + threadIdx.x;
  if(idx >= 32*dout) return;
  int b = idx / dout, j = idx - b*dout;
  float s = b2s[j];
  for(int ic=0; ic<NI; ic++) s += partial[((size_t)ic*32 + b)*dout + j];
  outp[idx] = s;
}

// ---------------- z / x_z, x1 / x_all mixers ----------------
__global__ __launch_bounds__(256) void zmix_kernel(
    const float* muo, const float* stdo, const float* eps1, const float* last, float* xz)
{
  int idx = blockIdx.x*256 + threadIdx.x;
  if(idx >= 4096) return;
  int b = idx >> 7, k = idx & 127;
  float z = muo[idx] + softplusf(stdo[idx] - 5.f)*eps1[idx];
  xz[b*256 + k]       = last[idx];
  xz[b*256 + 128 + k] = z;
}

__global__ __launch_bounds__(256) void xall_kernel(
    const float* muco, const float* stdco, const float* eps2, const float* x2f, float* xa)
{
  int idx = blockIdx.x*256 + threadIdx.x;
  if(idx >= 4096) return;
  int b = idx >> 7, k = idx & 127;
  xa[b*256 + k]       = muco[idx] + softplusf(stdco[idx] - 5.f)*eps2[idx];
  xa[b*256 + 128 + k] = x2f[idx];
}

// ---------------- causal conv1d partial sums (c-chunked, VALU-bound) ----------------
template<int CIN, int K, int COUT, int NCH, int LG>
__global__ __launch_bounds__(COUT*LG, 1) void convp_kernel(
    const float* __restrict__ xin, const float* __restrict__ w, float* __restrict__ part)
{
  constexpr int L = 32/LG;
  constexpr int CCH = CIN/NCH;
  __shared__ float xsh[CCH*32];
  int b = blockIdx.x, ch = blockIdx.y;
  int tid = threadIdx.x;
  for(int i=tid; i<CCH*32; i+=COUT*LG) xsh[i] = xin[((size_t)b*CIN + ch*CCH)*32 + i];
  __syncthreads();
  int o = tid / LG, lh = tid % LG;
  int l0 = lh*L;
  float acc[L];
  #pragma unroll
  for(int j=0;j<L;j++) acc[j]=0.f;
  const float* wrow = w + ((size_t)o*CIN + ch*CCH)*K;
  for(int c=0;c<CCH;c++){
    float wv[K];
    #pragma unroll
    for(int k=0;k<K;k++) wv[k] = wrow[c*K + k];
    float xr[L+K-1];
    #pragma unroll
    for(int i=0;i<L+K-1;i++){
      int li = l0 - (K-1) + i;
      xr[i] = (li>=0) ? xsh[c*32+li] : 0.f;
    }
    #pragma unroll
    for(int j=0;j<L;j++){
      #pragma unroll
      for(int k=0;k<K;k++) acc[j] = fmaf(xr[j+k], wv[k], acc[j]);
    }
  }
  float* pp = part + (((size_t)ch*32 + b)*COUT + o)*32 + l0;
  #pragma unroll
  for(int j=0;j<L;j++) pp[j] = acc[j];
}

// ---------------- SE fused with partial-reduce + BN + GELU ----------------
template<int C, int R, int NP>
__global__ __launch_bounds__(C,1) void sef_kernel(
    const float* __restrict__ part, const float* __restrict__ epi_s, const float* __restrict__ epi_b,
    const float* __restrict__ w1, const float* __restrict__ w2, float* __restrict__ out)
{
  __shared__ float mean[C];
  __shared__ float y1[R];
  int b = blockIdx.x, c = threadIdx.x;
  float g[32];
  #pragma unroll
  for(int l=0;l<32;l++) g[l]=0.f;
  for(int p=0;p<NP;p++){
    const float* pp = part + (((size_t)p*32 + b)*C + c)*32;
    #pragma unroll
    for(int l=0;l<32;l++) g[l] += pp[l];
  }
  float s = epi_s[c], bb = epi_b[c];
  float m = 0.f;
  #pragma unroll
  for(int l=0;l<32;l++){ g[l] = geluf(s*g[l]+bb); m += g[l]; }
  mean[c] = m*(1.f/32.f);
  __syncthreads();
  if(c < R){
    float t=0.f;
    for(int k=0;k<C;k++) t = fmaf(mean[k], w1[c*C+k], t);
    y1[c] = fmaxf(t,0.f);
  }
  __syncthreads();
  float t=0.f;
  #pragma unroll
  for(int k=0;k<R;k++) t = fmaf(y1[k], w2[c*R+k], t);
  float sc = sigmf(t);
  float* op = out + ((size_t)b*C + c)*32;
  #pragma unroll
  for(int l=0;l<32;l++) op[l] = g[l]*sc;
}

// ---------------- conv3 partial-reduce + BN + GELU + mean over l ----------------
__global__ __launch_bounds__(128,1) void mean3f_kernel(
    const float* __restrict__ part, const float* __restrict__ epi_s, const float* __restrict__ epi_b,
    float* __restrict__ x2f)
{
  int b = blockIdx.x, c = threadIdx.x;
  float g[32];
  #pragma unroll
  for(int l=0;l<32;l++) g[l]=0.f;
  for(int p=0;p<8;p++){
    const float* pp = part + (((size_t)p*32 + b)*128 + c)*32;
    #pragma unroll
    for(int l=0;l<32;l++) g[l] += pp[l];
  }
  float s = epi_s[c], bb = epi_b[c];
  float m = 0.f;
  #pragma unroll
  for(int l=0;l<32;l++) m += geluf(s*g[l]+bb);
  x2f[b*128 + c] = m*(1.f/32.f);
}

// ---------------- launch ----------------
extern "C" void kernel_launch(void* const* d_in, const int* in_sizes, int n_in,
                              void* d_out, int out_size, void* d_ws, size_t ws_size,
                              hipStream_t stream)
{
  const float* x    = (const float*)d_in[0];
  const float* we1  = (const float*)d_in[1];
  const float* be1  = (const float*)d_in[2];
  const float* e1g  = (const float*)d_in[3];
  const float* e1b  = (const float*)d_in[4];
  const float* e1m  = (const float*)d_in[5];
  const float* e1v  = (const float*)d_in[6];
  const float* we2  = (const float*)d_in[7];
  const float* be2  = (const float*)d_in[8];
  const float* e2g  = (const float*)d_in[9];
  const float* e2b  = (const float*)d_in[10];
  const float* e2m  = (const float*)d_in[11];
  const float* e2v  = (const float*)d_in[12];
  const float* wih  = (const float*)d_in[13];
  const float* whh  = (const float*)d_in[14];
  const float* bih  = (const float*)d_in[15];
  const float* bhh  = (const float*)d_in[16];
  const float* muW1 = (const float*)d_in[17];
  const float* muW2 = (const float*)d_in[18];
  const float* muB1 = (const float*)d_in[19];
  const float* muB2 = (const float*)d_in[20];
  const float* sdW1 = (const float*)d_in[21];
  const float* sdW2 = (const float*)d_in[22];
  const float* sdB1 = (const float*)d_in[23];
  const float* sdB2 = (const float*)d_in[24];
  const float* mcW1 = (const float*)d_in[25];
  const float* mcW2 = (const float*)d_in[26];
  const float* mcB1 = (const float*)d_in[27];
  const float* mcB2 = (const float*)d_in[28];
  const float* scW1 = (const float*)d_in[29];
  const float* scW2 = (const float*)d_in[30];
  const float* scB1 = (const float*)d_in[31];
  const float* scB2 = (const float*)d_in[32];
  const float* fcW1 = (const float*)d_in[33];
  const float* fcW2 = (const float*)d_in[34];
  const float* fcB1 = (const float*)d_in[35];
  const float* fcB2 = (const float*)d_in[36];
  const float* wc1  = (const float*)d_in[37];
  const float* bc1  = (const float*)d_in[38];
  const float* c1g  = (const float*)d_in[39];
  const float* c1b  = (const float*)d_in[40];
  const float* c1m  = (const float*)d_in[41];
  const float* c1v  = (const float*)d_in[42];
  const float* se1w1= (const float*)d_in[43];
  const float* se1w2= (const float*)d_in[44];
  const float* wc2  = (const float*)d_in[45];
  const float* bc2  = (const float*)d_in[46];
  const float* c2g  = (const float*)d_in[47];
  const float* c2b  = (const float*)d_in[48];
  const float* c2m  = (const float*)d_in[49];
  const float* c2v  = (const float*)d_in[50];
  const float* se2w1= (const float*)d_in[51];
  const float* se2w2= (const float*)d_in[52];
  const float* wc3  = (const float*)d_in[53];
  const float* bc3  = (const float*)d_in[54];
  const float* c3g  = (const float*)d_in[55];
  const float* c3b  = (const float*)d_in[56];
  const float* c3m  = (const float*)d_in[57];
  const float* c3v  = (const float*)d_in[58];
  const float* eps1 = (const float*)d_in[59];
  const float* eps2 = (const float*)d_in[60];

  float* ws = (float*)d_ws;
  float* part = ws + OFF_GX;   // gates_x region reused after lstm
  float* kp   = ws + OFF_KP;   // kan i-chunk partials (sequential reuse)
  float* b2s  = ws + OFF_B2S;

  prep_kernel<<<2448, 256, 0, stream>>>(we1, be1, e1g,e1b,e1m,e1v,
      we2, be2,e2g,e2b,e2m,e2v, wih,whh,bih,bhh,
      bc1,c1g,c1b,c1m,c1v, bc2,c2g,c2b,c2m,c2v, bc3,c3g,c3b,c3m,c3v,
      muB2, sdB2, mcB2, scB2, fcB2, ws);

  encoder_kernel<<<256, 256, 0, stream>>>(x, ws+OFF_W1F, ws+OFF_B1F,
      ws+OFF_S2E, ws+OFF_B2E, (const bf16*)(ws+OFF_WE2B), ws+OFF_XSRC);

  gates_kernel<<<256, 256, 0, stream>>>(ws+OFF_XSRC, ws+OFF_WIHT, ws+OFF_BIASG, ws+OFF_GX);
  lstm_kernel<<<32, 256, 0, stream>>>(ws+OFF_GX, ws+OFF_WHHT, ws+OFF_HSEQ);

  hn_kernel<<<8192, 64, 0, stream>>>(ws+OFF_HSEQ, ws+OFF_HN);
  pc_kernel<<<256, 256, 0, stream>>>(ws+OFF_HN, ws+OFF_PCOL, ws+OFF_CCOL);
  cutcorr_kernel<<<32, 256, 0, stream>>>(ws+OFF_PCOL, ws+OFF_CCOL, ws+OFF_HSEQ,
      ws+OFF_LAST, ws+OFF_CORR, (int*)(ws+OFF_CUTS));

  feat_kernel<<<16, 256, 0, stream>>>(ws+OFF_CORR, ws+OFF_FEATA, 4096);
  kanp_kernel<<<dim3(128,4), 256, 0, stream>>>(ws+OFF_FEATA, muW1, muB1, muW2, 128, 128, kp);
  kanr_kernel<<<16, 256, 0, stream>>>(kp, b2s+0, 4, 128, ws+OFF_MUO);
  kanp_kernel<<<dim3(128,4), 256, 0, stream>>>(ws+OFF_FEATA, sdW1, sdB1, sdW2, 128, 128, kp);
  kanr_kernel<<<16, 256, 0, stream>>>(kp, b2s+128, 4, 128, ws+OFF_STDO);
  zmix_kernel<<<16, 256, 0, stream>>>(ws+OFF_MUO, ws+OFF_STDO, eps1, ws+OFF_LAST, ws+OFF_XZ);
  feat_kernel<<<32, 256, 0, stream>>>(ws+OFF_XZ, ws+OFF_FEATB, 8192);
  kanp_kernel<<<dim3(128,8), 256, 0, stream>>>(ws+OFF_FEATB, mcW1, mcB1, mcW2, 256, 128, kp);
  kanr_kernel<<<16, 256, 0, stream>>>(kp, b2s+256, 8, 128, ws+OFF_MUCO);
  kanp_kernel<<<dim3(128,8), 256, 0, stream>>>(ws+OFF_FEATB, scW1, scB1, scW2, 256, 128, kp);
  kanr_kernel<<<16, 256, 0, stream>>>(kp, b2s+384, 8, 128, ws+OFF_STDCO);

  convp_kernel<256,8,128,8,2><<<dim3(32,8), 256, 0, stream>>>(x, wc1, part);
  sef_kernel<128,8,8><<<32, 128, 0, stream>>>(part, ws+OFF_EPI1S, ws+OFF_EPI1B, se1w1, se1w2, ws+OFF_XC1);
  convp_kernel<128,5,256,4,1><<<dim3(32,4), 256, 0, stream>>>(ws+OFF_XC1, wc2, part);
  sef_kernel<256,16,4><<<32, 256, 0, stream>>>(part, ws+OFF_EPI2S, ws+OFF_EPI2B, se2w1, se2w2, ws+OFF_XC2);
  convp_kernel<256,3,128,8,2><<<dim3(32,8), 256, 0, stream>>>(ws+OFF_XC2, wc3, part);
  mean3f_kernel<<<32, 128, 0, stream>>>(part, ws+OFF_EPI3S, ws+OFF_EPI3B, ws+OFF_X2F);

  xall_kernel<<<16, 256, 0, stream>>>(ws+OFF_MUCO, ws+OFF_STDCO, eps2, ws+OFF_X2F, ws+OFF_XALL);
  feat_kernel<<<32, 256, 0, stream>>>(ws+OFF_XALL, ws+OFF_FEATC, 8192);
  kanp_kernel<<<dim3(10,8), 256, 0, stream>>>(ws+OFF_FEATC, fcW1, fcB1, fcW2, 256, 10, kp);
  kanr_kernel<<<2, 256, 0, stream>>>(kp, b2s+512, 8, 10, (float*)d_out);
}